// Round 11
// baseline (4145.642 us; speedup 1.0000x reference)
//
#include <hip/hip_runtime.h>
#include <hip/hip_bf16.h>

typedef __attribute__((ext_vector_type(8))) short bf16x8;
typedef __attribute__((ext_vector_type(4))) float f32x4;
typedef __attribute__((ext_vector_type(4))) unsigned u32x4;

#define HD   768
#define NB   64
#define NT   256
#define NGATE 3072   // 4*HD
#define FPAD 32      // flag padding: 32 ints = 128 B (one cache line)

__device__ __forceinline__ float fast_sig(float x) { return 1.f / (1.f + __expf(-x)); }
__device__ __forceinline__ float fast_tanh(float x) {
  float t = __expf(-2.f * fabsf(x));
  float r = (1.f - t) / (1.f + t);
  return x < 0.f ? -r : r;
}
__device__ __forceinline__ float bf2f(unsigned short u) {
  union { unsigned i; float f; } v; v.i = ((unsigned)u) << 16; return v.f;
}
__device__ __forceinline__ unsigned short f2bfu(float f) {
  union { __hip_bfloat16 b; unsigned short u; } c;
  c.b = __float2bfloat16(f);
  return c.u;
}
__device__ __forceinline__ unsigned pack2(float a, float b) {
  return (unsigned)f2bfu(a) | ((unsigned)f2bfu(b) << 16);
}

#define VMW(N) do { asm volatile("s_waitcnt vmcnt(" #N ")" ::: "memory"); \
                    __builtin_amdgcn_sched_barrier(0); } while (0)

// ---------------------------------------------------------------------------
// Coherent-path primitives (LLC, bypass non-cross-coherent per-XCD L2).
// ---------------------------------------------------------------------------
__device__ __forceinline__ int aload(int* p) {
  return __hip_atomic_load(p, __ATOMIC_RELAXED, __HIP_MEMORY_SCOPE_AGENT);
}
__device__ __forceinline__ void ustore(unsigned* p, unsigned v) {
  __hip_atomic_store(p, v, __ATOMIC_RELAXED, __HIP_MEMORY_SCOPE_AGENT);
}
// wide coherent load: 16B, served at the coherent point
__device__ __forceinline__ u32x4 cload16(const char* p) {
  u32x4 r;
  asm volatile("global_load_dwordx4 %0, %1, off sc0 sc1"
               : "=v"(r) : "v"(p) : "memory");
  return r;
}

// Publish: drain this thread's (write-through) stores, block barrier, flag RMW.
__device__ __forceinline__ void arrive_flag(int* f) {
  asm volatile("s_waitcnt vmcnt(0)" ::: "memory");
  __syncthreads();
  if (threadIdx.x == 0)
    __hip_atomic_fetch_add(f, 1, __ATOMIC_RELAXED, __HIP_MEMORY_SCOPE_AGENT);
}

// Wait until all 96 flags in fa >= ta AND (fb: all 96 flags in fb >= tb).
__device__ __forceinline__ void wait2(int* fa, int ta, int* fb, int tb) {
  int tid = threadIdx.x;
  int* p = nullptr; int tgt = 0;
  if (tid < 96)                            { p = fa + tid * FPAD;         tgt = ta; }
  else if (fb && tid >= 128 && tid < 224)  { p = fb + (tid - 128) * FPAD; tgt = tb; }
  if (p && tgt > 0) {
    int guard = 0;
    while (aload(p) < tgt) {
      __builtin_amdgcn_s_sleep(1);
      if (++guard > (1 << 17)) break;      // deadlock -> fast wrong answer, not hang
    }
  }
  __syncthreads();                         // all flags observed; compiler fence
}

// ---------------------------------------------------------------------------
// Frag exchange layout: 16B chunk (it, rg, l) at byte ((it*4+rg)*64+l)*16.
// Producer of k-pair (j,j+1), batch b writes one dword:
// ---------------------------------------------------------------------------
__device__ __forceinline__ int frag_dw(int b, int j) {
  return (((((j >> 5) * 4 + (b >> 4)) * 4 + ((j >> 3) & 3)) * 16 + (b & 15)) * 4)
         + ((j & 7) >> 1);
}

// W LDS swizzle, full-rank: bits 4-6 from r&7, bits 7-8 from (r>>3)&3.
__device__ __forceinline__ int wswz(int r) {
  return ((r & 7) << 4) | (((r >> 3) & 3) << 7);
}

__device__ __forceinline__ void load_W_lds(unsigned short* Wl,
                                           const __hip_bfloat16* Wg,
                                           int n_base, int K)
{
  int chunksPerRow = (K * 2) / 16;
  int total = 32 * chunksPerRow;
  for (int idx = threadIdx.x; idx < total; idx += 256) {
    int r  = idx / chunksPerRow;
    int cb = (idx % chunksPerRow) * 16;
    bf16x8 v = *(const bf16x8*)((const char*)(Wg + (long)(n_base + r) * K) + cb);
    *(bf16x8*)((char*)Wl + (long)r * (K * 2) + (cb ^ wswz(r))) = v;
  }
}

// ---------------------------------------------------------------------------
// Cached-A MFMA range [kbase, kbase+NIT) (read-only global data)
// ---------------------------------------------------------------------------
__device__ __forceinline__ void mfma_cached(
    const __hip_bfloat16* a0p, int kbase, int NIT,
    const char* w0, const char* w1, int xr0, int xr1, int kk,
    f32x4& acc0, f32x4& acc1)
{
  #pragma unroll 4
  for (int it = kbase; it < kbase + NIT; ++it) {
    bf16x8 av = *(const bf16x8*)(a0p + it * 32 + kk);
    int oo = (it * 32 + kk) * 2;
    bf16x8 bv0 = *(const bf16x8*)(w0 + (oo ^ xr0));
    bf16x8 bv1 = *(const bf16x8*)(w1 + (oo ^ xr1));
    acc0 = __builtin_amdgcn_mfma_f32_16x16x32_bf16(av, bv0, acc0, 0, 0, 0);
    acc1 = __builtin_amdgcn_mfma_f32_16x16x32_bf16(av, bv1, acc1, 0, 0, 0);
  }
}

// Issue 12 coherent 16B frag loads (chunk c0..c0+11) into a register array.
__device__ __forceinline__ void issue12(u32x4* dst, const char* base, int c0) {
  #pragma unroll
  for (int i = 0; i < 12; ++i)
    dst[i] = cload16(base + (size_t)(c0 + i) * 4096);
}

// Compute 12 staged frag iterations (loads already waited).
__device__ __forceinline__ void mfma_st12(
    const u32x4* st, int kbase,
    const char* w0, const char* w1, int xr0, int xr1, int kk,
    f32x4& acc0, f32x4& acc1)
{
  #pragma unroll
  for (int i = 0; i < 12; ++i) {
    int oo = ((kbase + i) * 32 + kk) * 2;
    bf16x8 av = __builtin_bit_cast(bf16x8, st[i]);
    bf16x8 bv0 = *(const bf16x8*)(w0 + (oo ^ xr0));
    bf16x8 bv1 = *(const bf16x8*)(w1 + (oo ^ xr1));
    acc0 = __builtin_amdgcn_mfma_f32_16x16x32_bf16(av, bv0, acc0, 0, 0, 0);
    acc1 = __builtin_amdgcn_mfma_f32_16x16x32_bf16(av, bv1, acc1, 0, 0, 0);
  }
}

// ---------------------------------------------------------------------------
// Fused setup: convert x to bf16 + pack all 4 weight matrices (one launch).
// ---------------------------------------------------------------------------
__device__ __forceinline__ void pack_seg(const float* Wih, const float* Whh,
                                         __hip_bfloat16* dst, int Kih,
                                         long id0, long stride)
{
  int K = Kih + HD;
  long total = (long)NGATE * K;
  for (long idx = id0; idx < total; idx += stride) {
    int np = (int)(idx / K), k = (int)(idx % K);
    int j = np >> 2, g = np & 3;
    int n = g * HD + j;
    float v = (k < Kih) ? Wih[(long)n * Kih + k] : Whh[(long)n * HD + (k - Kih)];
    dst[idx] = __float2bfloat16(v);
  }
}

__global__ void setup_kernel(
    const float* __restrict__ x,
    const float* __restrict__ WihF, const float* __restrict__ WhhF,
    const float* __restrict__ WihB, const float* __restrict__ WhhB,
    const float* __restrict__ WihS, const float* __restrict__ WhhS,
    const float* __restrict__ WihW, const float* __restrict__ WhhW,
    __hip_bfloat16* __restrict__ X16,
    __hip_bfloat16* __restrict__ WF, __hip_bfloat16* __restrict__ WB,
    __hip_bfloat16* __restrict__ WS, __hip_bfloat16* __restrict__ WW)
{
  long id0 = (long)blockIdx.x * blockDim.x + threadIdx.x;
  long stride = (long)gridDim.x * blockDim.x;
  for (long i = id0; i < (long)NB * NT * HD; i += stride)
    X16[i] = __float2bfloat16(x[i]);
  pack_seg(WihF, WhhF, WF, 768, id0, stride);
  pack_seg(WihB, WhhB, WB, 768, id0, stride);
  pack_seg(WihS, WhhS, WS, 1536, id0, stride);
  pack_seg(WihW, WhhW, WW, 1536, id0, stride);
}

__global__ void fill_sentinel(float* out, int n, float v)
{
  int i = blockIdx.x * blockDim.x + threadIdx.x;
  if (i < n) out[i] = v;
}

// ---------------------------------------------------------------------------
// Phase 1 persistent: BiLSTM, 192 blocks (0-95 fwd, 96-191 bwd), 256 steps.
// Per step: cached X16 12 its (covers poll) -> wait -> issue 24 H loads ->
// cached X16 12 its (covers LLC latency) -> vmcnt(0) -> 24 staged its.
// ---------------------------------------------------------------------------
__global__ __launch_bounds__(256, 1) void bilstm_persist(
    const __hip_bfloat16* __restrict__ X16,   // [64][256][768]
    const __hip_bfloat16* __restrict__ WF,
    const __hip_bfloat16* __restrict__ WB,
    const float* __restrict__ bF, const float* __restrict__ bB,
    unsigned* __restrict__ H16u,              // [2 par][2 dir] frag 98304B
    __hip_bfloat16* __restrict__ L16,         // [64][256][1536]
    int* __restrict__ flags)                  // [2 dir][96*FPAD]
{
  __shared__ unsigned short Wl[32 * 1536];    // 96 KiB
  __shared__ float gl[64][33];
  int blk = blockIdx.x, dir = blk / 96, nt = blk % 96;
  load_W_lds(Wl, dir ? WB : WF, nt * 32, 1536);
  const float* bias = dir ? bB : bF;
  int* myflags = flags + dir * 96 * FPAD;
  int tid = threadIdx.x;
  unsigned* L16u = (unsigned*)L16;

  int w = tid >> 6, l = tid & 63, lr = l & 15, lh = l >> 4;
  const char* w0 = (const char*)Wl + lr * 3072;
  const char* w1 = (const char*)Wl + (16 + lr) * 3072;
  int xr0 = wswz(lr), xr1 = wswz(16 + lr);
  int kk = 8 * lh;
  int bA = 16 * w + lr;

  int e0 = tid * 2;
  int b = e0 >> 3, jj = e0 & 7;        // jj even
  int j0 = nt * 8 + jj;
  float bv[2][4];
  #pragma unroll
  for (int u = 0; u < 2; ++u) {
    bv[u][0] = bias[j0 + u];          bv[u][1] = bias[HD + j0 + u];
    bv[u][2] = bias[2 * HD + j0 + u]; bv[u][3] = bias[3 * HD + j0 + u];
  }
  int fdw = frag_dw(b, j0);
  float cst[2] = {0.f, 0.f};
  __syncthreads();

  for (int s = 0; s < NT; ++s) {
    int par = s & 1;
    int t = dir ? (NT - 1 - s) : s;
    const __hip_bfloat16* xb = X16 + (long)t * HD + (long)bA * (NT * HD);
    f32x4 acc0 = {0.f, 0.f, 0.f, 0.f};
    f32x4 acc1 = {0.f, 0.f, 0.f, 0.f};
    mfma_cached(xb, 0, 12, w0, w1, xr0, xr1, kk, acc0, acc1);   // covers poll
    if (s > 0) wait2(myflags, s, nullptr, 0);
    const char* fpH = (const char*)(H16u + (long)(par * 2 + dir) * 24576)
                      + (size_t)(w * 64 + l) * 16;
    u32x4 hA[12], hB[12];
    issue12(hA, fpH, 0);
    issue12(hB, fpH, 12);
    mfma_cached(xb, 12, 12, w0, w1, xr0, xr1, kk, acc0, acc1);  // covers latency
    VMW(0);
    mfma_st12(hA, 24, w0, w1, xr0, xr1, kk, acc0, acc1);
    mfma_st12(hB, 36, w0, w1, xr0, xr1, kk, acc0, acc1);
    #pragma unroll
    for (int r = 0; r < 4; ++r) {
      gl[16 * w + 4 * lh + r][lr]      = acc0[r];
      gl[16 * w + 4 * lh + r][16 + lr] = acc1[r];
    }
    __syncthreads();
    float hv[2];
    #pragma unroll
    for (int u = 0; u < 2; ++u) {
      int col = 4 * (jj + u);
      float vi = gl[b][col + 0] + bv[u][0];
      float vf = gl[b][col + 1] + bv[u][1];
      float vg = gl[b][col + 2] + bv[u][2];
      float vo = gl[b][col + 3] + bv[u][3];
      float si = fast_sig(vi), sf = fast_sig(vf), so = fast_sig(vo);
      float tg = fast_tanh(vg);
      float c = sf * cst[u] + si * tg;
      cst[u] = c;
      hv[u] = so * fast_tanh(c);
    }
    unsigned pk = pack2(hv[0], hv[1]);
    ustore(H16u + (long)((par ^ 1) * 2 + dir) * 24576 + fdw, pk);
    L16u[((long)b * NT + t) * 768 + dir * 384 + (j0 >> 1)] = pk;  // cached (kernel-end flush)
    if (s < NT - 1) arrive_flag(myflags + nt * FPAD);
  }
}

// ---------------------------------------------------------------------------
// cls x-part + pred0; all 256 threads used (k-split halves + shfl reduce)
// ---------------------------------------------------------------------------
__global__ __launch_bounds__(256) void clsx_kernel(
    const __hip_bfloat16* __restrict__ L16,
    const float* __restrict__ clsW, const float* __restrict__ clsb,
    float* __restrict__ out)
{
  int t = blockIdx.x;
  int tid = threadIdx.x;
  int b = tid >> 2, o = (tid >> 1) & 1, hh = tid & 1;
  if (t == 0) {
    if (hh == 0) out[((long)b * NT) * 2 + o] = o ? 1.f : -1.f;
    return;
  }
  const bf16x8* xp = (const bf16x8*)(L16 + ((long)b * NT + t) * 1536 + hh * 768);
  const float* wv = clsW + o * 2304 + HD + hh * 768;
  float s = 0.f;
  for (int k = 0; k < 96; ++k) {
    bf16x8 v = xp[k];
    #pragma unroll
    for (int e = 0; e < 8; ++e)
      s += bf2f((unsigned short)v[e]) * wv[k * 8 + e];
  }
  s += __shfl_down(s, 1);
  if (hh == 0) out[((long)b * NT + t) * 2 + o] = s + clsb[o];
}

// ---------------------------------------------------------------------------
// Phase 2 persistent: 192 blocks (0-95 subword chain, 96-191 word chain),
// producer-consumer via 4-deep SUBW frag ring + flag arrays.
//   subword step s: cached 24 (covers poll); wait flagS>=s & flagW>=s-3;
//                   issue 24 H1 loads; cached 24 (cover); vmcnt(0); staged 24.
//   word    step s: wait flagW>=s; issue 24 H2; wait flagS>=s+1 (loads fly);
//                   3x12 rotating pipeline over 48 SUBW its, counted vmcnt.
// ---------------------------------------------------------------------------
__global__ __launch_bounds__(256, 1) void stack_persist(
    const __hip_bfloat16* __restrict__ L16,
    const __hip_bfloat16* __restrict__ WS,
    const __hip_bfloat16* __restrict__ WW,
    const float* __restrict__ bS, const float* __restrict__ bW,
    const int* __restrict__ golds,
    const float* __restrict__ clsW,
    unsigned* __restrict__ H1Su,   // [2] frag 98304B
    unsigned* __restrict__ H2Su,   // [2] frag 98304B
    unsigned* __restrict__ SUBWu,  // [4] frag 196608B ring (h1 k<768, c1 768..1536)
    float* __restrict__ out,
    int* __restrict__ flags)       // [+2*96*FPAD: S] [+3*96*FPAD: W]
{
  __shared__ unsigned short Wl[32 * 2304];  // 144 KiB
  __shared__ float gl[64][33];
  int blk = blockIdx.x, role = blk / 96, nt = blk % 96;
  int* flagS = flags + 2 * 96 * FPAD;
  int* flagW = flags + 3 * 96 * FPAD;
  const float* bias = role ? bW : bS;
  load_W_lds(Wl, role ? WW : WS, nt * 32, 2304);
  int tid = threadIdx.x;

  int w = tid >> 6, l = tid & 63, lr = l & 15, lh = l >> 4;
  const char* w0 = (const char*)Wl + lr * 4608;
  const char* w1 = (const char*)Wl + (16 + lr) * 4608;
  int xr0 = wswz(lr), xr1 = wswz(16 + lr);
  int kk = 8 * lh;
  int bA = 16 * w + lr;

  int e0 = tid * 2;
  int b = e0 >> 3, jj = e0 & 7;        // jj even
  int j0 = nt * 8 + jj;
  float bv[2][4];
  #pragma unroll
  for (int u = 0; u < 2; ++u) {
    bv[u][0] = bias[j0 + u];          bv[u][1] = bias[HD + j0 + u];
    bv[u][2] = bias[2 * HD + j0 + u]; bv[u][3] = bias[3 * HD + j0 + u];
  }
  const int* gp = golds + b * NT + 1;   // gp[s] = golds[b][s+1]
  int fdw_h = frag_dw(b, j0);
  float cst[2] = {0.f, 0.f};
  float hreg[2] = {0.f, 0.f};
  __syncthreads();

  if (role == 0) {
    // ---- subword chain ----
    int fdw_c = frag_dw(b, 768 + j0);   // c1 at k 768.. in SUBW frag
    for (int s = 0; s < NT - 1; ++s) {
      int g = gp[s];                    // older-than-staging load: safe
      const __hip_bfloat16* lb = L16 + (long)s * 1536 + (long)bA * (NT * 1536);
      f32x4 acc0 = {0.f, 0.f, 0.f, 0.f};
      f32x4 acc1 = {0.f, 0.f, 0.f, 0.f};
      mfma_cached(lb, 0, 24, w0, w1, xr0, xr1, kk, acc0, acc1);   // covers poll
      wait2(flagS, s, flagW, s - 3);
      const char* fpH1 = (const char*)(H1Su + (long)(s & 1) * 24576)
                         + (size_t)(w * 64 + l) * 16;
      u32x4 hA[12], hB[12];
      issue12(hA, fpH1, 0);
      issue12(hB, fpH1, 12);
      mfma_cached(lb, 24, 24, w0, w1, xr0, xr1, kk, acc0, acc1);  // covers latency
      VMW(0);
      mfma_st12(hA, 48, w0, w1, xr0, xr1, kk, acc0, acc1);
      mfma_st12(hB, 60, w0, w1, xr0, xr1, kk, acc0, acc1);
      #pragma unroll
      for (int r = 0; r < 4; ++r) {
        gl[16 * w + 4 * lh + r][lr]      = acc0[r];
        gl[16 * w + 4 * lh + r][16 + lr] = acc1[r];
      }
      __syncthreads();
      float h1v[2], c1v[2];
      #pragma unroll
      for (int u = 0; u < 2; ++u) {
        int col = 4 * (jj + u);
        float vi = gl[b][col + 0] + bv[u][0];
        float vf = gl[b][col + 1] + bv[u][1];
        float vg = gl[b][col + 2] + bv[u][2];
        float vo = gl[b][col + 3] + bv[u][3];
        float si = fast_sig(vi), sf = fast_sig(vf), so = fast_sig(vo);
        float tg = fast_tanh(vg);
        c1v[u] = sf * cst[u] + si * tg;
        h1v[u] = so * fast_tanh(c1v[u]);
      }
      bool push = (g == 0);
      unsigned pkh = pack2(h1v[0], h1v[1]);
      unsigned pkc = pack2(c1v[0], c1v[1]);
      unsigned* sb = SUBWu + (long)(s & 3) * 49152;
      ustore(sb + fdw_h, pkh);
      ustore(sb + fdw_c, pkc);
      ustore(H1Su + (long)((s + 1) & 1) * 24576 + fdw_h, push ? pkh : 0u);
      cst[0] = push ? c1v[0] : 0.f;
      cst[1] = push ? c1v[1] : 0.f;
      arrive_flag(flagS + nt * FPAD);
    }
  } else {
    // ---- word chain: 3x12 rotating deep-prefetch pipeline (36 in flight) ----
    float cw0[2], cw1[2];
    #pragma unroll
    for (int u = 0; u < 2; ++u) { cw0[u] = clsW[j0 + u]; cw1[u] = clsW[2304 + j0 + u]; }
    for (int s = 0; s < NT - 1; ++s) {
      int g = gp[s];                    // older-than-staging load: safe
      wait2(flagW, s, nullptr, 0);      // self-chain: usually already set
      const char* fpH = (const char*)(H2Su + (long)(s & 1) * 24576)
                        + (size_t)(w * 64 + l) * 16;
      const char* fpS = (const char*)(SUBWu + (long)(s & 3) * 49152)
                        + (size_t)(w * 64 + l) * 16;
      u32x4 sA[12], sB[12], sC[12];
      issue12(sA, fpH, 0);              // H2 its 48..59
      issue12(sB, fpH, 12);             // H2 its 60..71
      wait2(flagS, s + 1, nullptr, 0);  // H2 loads drain during poll
      issue12(sC, fpS, 0);              // SUBW its 0..11
      f32x4 acc0 = {0.f, 0.f, 0.f, 0.f};
      f32x4 acc1 = {0.f, 0.f, 0.f, 0.f};
      VMW(24);
      mfma_st12(sA, 48, w0, w1, xr0, xr1, kk, acc0, acc1);
      issue12(sA, fpS, 12);             // SUBW its 12..23
      VMW(24);
      mfma_st12(sB, 60, w0, w1, xr0, xr1, kk, acc0, acc1);
      issue12(sB, fpS, 24);             // SUBW its 24..35
      VMW(24);
      mfma_st12(sC, 0, w0, w1, xr0, xr1, kk, acc0, acc1);
      issue12(sC, fpS, 36);             // SUBW its 36..47
      VMW(24);
      mfma_st12(sA, 12, w0, w1, xr0, xr1, kk, acc0, acc1);
      VMW(12);
      mfma_st12(sB, 24, w0, w1, xr0, xr1, kk, acc0, acc1);
      VMW(0);
      mfma_st12(sC, 36, w0, w1, xr0, xr1, kk, acc0, acc1);
      #pragma unroll
      for (int r = 0; r < 4; ++r) {
        gl[16 * w + 4 * lh + r][lr]      = acc0[r];
        gl[16 * w + 4 * lh + r][16 + lr] = acc1[r];
      }
      __syncthreads();
      float p0 = 0.f, p1 = 0.f;
      float h2v[2], c2v[2];
      #pragma unroll
      for (int u = 0; u < 2; ++u) {
        int col = 4 * (jj + u);
        float vi = gl[b][col + 0] + bv[u][0];
        float vf = gl[b][col + 1] + bv[u][1];
        float vg = gl[b][col + 2] + bv[u][2];
        float vo = gl[b][col + 3] + bv[u][3];
        float si = fast_sig(vi), sf = fast_sig(vf), so = fast_sig(vo);
        float tg = fast_tanh(vg);
        c2v[u] = sf * cst[u] + si * tg;
        h2v[u] = so * fast_tanh(c2v[u]);
        p0 += h2v[u] * cw0[u];
        p1 += h2v[u] * cw1[u];
      }
      bool push = (g >= 1);
      #pragma unroll
      for (int u = 0; u < 2; ++u) {
        cst[u]  = push ? c2v[u] : cst[u];
        hreg[u] = push ? h2v[u] : hreg[u];
      }
      ustore(H2Su + (long)((s + 1) & 1) * 24576 + fdw_h, pack2(hreg[0], hreg[1]));
      p0 += __shfl_down(p0, 1); p1 += __shfl_down(p1, 1);
      p0 += __shfl_down(p0, 2); p1 += __shfl_down(p1, 2);
      if ((tid & 3) == 0) {
        int bb = tid >> 2;
        atomicAdd(&out[((long)bb * NT + s + 1) * 2 + 0], p0);
        atomicAdd(&out[((long)bb * NT + s + 1) * 2 + 1], p1);
      }
      if (s < NT - 2) arrive_flag(flagW + nt * FPAD);
    }
  }
}

// ---------------------------------------------------------------------------
// Host launcher
// ---------------------------------------------------------------------------
extern "C" void kernel_launch(void* const* d_in, const int* in_sizes, int n_in,
                              void* d_out, int out_size, void* d_ws, size_t ws_size,
                              hipStream_t stream)
{
  const float* x     = (const float*)d_in[0];
  const int*   golds = (const int*)d_in[1];
  const float* WihF  = (const float*)d_in[2];
  const float* WhhF  = (const float*)d_in[3];
  const float* bF    = (const float*)d_in[4];
  const float* WihB  = (const float*)d_in[5];
  const float* WhhB  = (const float*)d_in[6];
  const float* bB    = (const float*)d_in[7];
  const float* WihS  = (const float*)d_in[8];
  const float* WhhS  = (const float*)d_in[9];
  const float* bS    = (const float*)d_in[10];
  const float* WihW  = (const float*)d_in[11];
  const float* WhhW  = (const float*)d_in[12];
  const float* bW    = (const float*)d_in[13];
  const float* clsW  = (const float*)d_in[14];
  const float* clsb  = (const float*)d_in[15];
  float* out = (float*)d_out;

  // workspace layout (bytes)
  const size_t OFF_X16  = 0;                   // 25165824
  const size_t OFF_WF   = 25165824;            //  9437184
  const size_t OFF_WB   = 34603008;            //  9437184
  const size_t OFF_WS   = 44040192;            // 14155776
  const size_t OFF_WW   = 58195968;            // 14155776
  const size_t OFF_L16  = 72351744;            // 50331648
  const size_t OFF_H16  = 122683392;           //   393216 (frag [2][2])
  const size_t OFF_H1S  = 123076608;           //   196608 (frag [2])
  const size_t OFF_H2S  = 123273216;           //   196608 (frag [2])
  const size_t OFF_SUBW = 123469824;           //   786432 (frag ring [4])
  const size_t OFF_FLG  = 124256256;           //    49152 (4*96*128B)
  const size_t WS_NEEDED = 124305408;

  if (ws_size < WS_NEEDED) {
    fill_sentinel<<<(out_size + 255) / 256, 256, 0, stream>>>(out, out_size, 12345.f);
    return;
  }

  char* ws = (char*)d_ws;
  __hip_bfloat16* X16  = (__hip_bfloat16*)(ws + OFF_X16);
  __hip_bfloat16* WF   = (__hip_bfloat16*)(ws + OFF_WF);
  __hip_bfloat16* WB   = (__hip_bfloat16*)(ws + OFF_WB);
  __hip_bfloat16* WSp  = (__hip_bfloat16*)(ws + OFF_WS);
  __hip_bfloat16* WWp  = (__hip_bfloat16*)(ws + OFF_WW);
  __hip_bfloat16* L16  = (__hip_bfloat16*)(ws + OFF_L16);
  unsigned*       H16u = (unsigned*)(ws + OFF_H16);
  unsigned*       H1Su = (unsigned*)(ws + OFF_H1S);
  unsigned*       H2Su = (unsigned*)(ws + OFF_H2S);
  unsigned*       SUBWu= (unsigned*)(ws + OFF_SUBW);
  int*            flags= (int*)(ws + OFF_FLG);

  // fused setup: cvt x + pack all 4 weight matrices (one launch)
  setup_kernel<<<4096, 256, 0, stream>>>(x, WihF, WhhF, WihB, WhhB,
                                         WihS, WhhS, WihW, WhhW,
                                         X16, WF, WB, WSp, WWp);
  hipMemsetAsync(ws + OFF_H16, 0, WS_NEEDED - OFF_H16, stream);

  // phase 1: persistent BiLSTM (256 internal flag-sync steps)
  bilstm_persist<<<192, 256, 0, stream>>>(X16, WF, WB, bF, bB, H16u, L16, flags);

  // cls x-part + pred0 (full overwrite of out)
  clsx_kernel<<<NT, 256, 0, stream>>>(L16, clsW, clsb, out);

  // phase 2: persistent stack-LSTM, subword/word chains pipelined
  stack_persist<<<192, 256, 0, stream>>>(L16, WSp, WWp, bS, bW, golds, clsW,
                                         H1Su, H2Su, SUBWu, out, flags);
}

// Round 12
// 4143.918 us; speedup vs baseline: 1.0004x; 1.0004x over previous
//
#include <hip/hip_runtime.h>
#include <hip/hip_bf16.h>

typedef __attribute__((ext_vector_type(8))) short bf16x8;
typedef __attribute__((ext_vector_type(4))) float f32x4;
typedef __attribute__((ext_vector_type(4))) unsigned u32x4;

#define HD   768
#define NB   64
#define NT   256
#define NGATE 3072   // 4*HD
#define FPAD 32      // flag padding: 32 ints = 128 B (one cache line)

__device__ __forceinline__ float fast_sig(float x) { return 1.f / (1.f + __expf(-x)); }
__device__ __forceinline__ float fast_tanh(float x) {
  float t = __expf(-2.f * fabsf(x));
  float r = (1.f - t) / (1.f + t);
  return x < 0.f ? -r : r;
}
__device__ __forceinline__ float bf2f(unsigned short u) {
  union { unsigned i; float f; } v; v.i = ((unsigned)u) << 16; return v.f;
}
__device__ __forceinline__ unsigned short f2bfu(float f) {
  union { __hip_bfloat16 b; unsigned short u; } c;
  c.b = __float2bfloat16(f);
  return c.u;
}
__device__ __forceinline__ unsigned pack2(float a, float b) {
  return (unsigned)f2bfu(a) | ((unsigned)f2bfu(b) << 16);
}

#define VMW(N) do { asm volatile("s_waitcnt vmcnt(" #N ")" ::: "memory"); \
                    __builtin_amdgcn_sched_barrier(0); } while (0)

// ---------------------------------------------------------------------------
// Coherent-path primitives (LLC, bypass non-cross-coherent per-XCD L2).
// ---------------------------------------------------------------------------
__device__ __forceinline__ int aload(int* p) {
  return __hip_atomic_load(p, __ATOMIC_RELAXED, __HIP_MEMORY_SCOPE_AGENT);
}
__device__ __forceinline__ void ustore(unsigned* p, unsigned v) {
  __hip_atomic_store(p, v, __ATOMIC_RELAXED, __HIP_MEMORY_SCOPE_AGENT);
}
// wide coherent load: 16B, served at the coherent point
__device__ __forceinline__ u32x4 cload16(const char* p) {
  u32x4 r;
  asm volatile("global_load_dwordx4 %0, %1, off sc0 sc1"
               : "=v"(r) : "v"(p) : "memory");
  return r;
}

// Publish: drain this thread's (write-through) stores, block barrier, flag RMW.
__device__ __forceinline__ void arrive_flag(int* f) {
  asm volatile("s_waitcnt vmcnt(0)" ::: "memory");
  __syncthreads();
  if (threadIdx.x == 0)
    __hip_atomic_fetch_add(f, 1, __ATOMIC_RELAXED, __HIP_MEMORY_SCOPE_AGENT);
}

// Wait until all 96 flags in fa >= ta AND (fb: all 96 flags in fb >= tb).
__device__ __forceinline__ void wait2(int* fa, int ta, int* fb, int tb) {
  int tid = threadIdx.x;
  int* p = nullptr; int tgt = 0;
  if (tid < 96)                            { p = fa + tid * FPAD;         tgt = ta; }
  else if (fb && tid >= 128 && tid < 224)  { p = fb + (tid - 128) * FPAD; tgt = tb; }
  if (p && tgt > 0) {
    int guard = 0;
    while (aload(p) < tgt) {
      __builtin_amdgcn_s_sleep(1);
      if (++guard > (1 << 17)) break;      // deadlock -> fast wrong answer, not hang
    }
  }
  __syncthreads();                         // all flags observed; compiler fence
}

// ---------------------------------------------------------------------------
// Frag exchange layout: 16B chunk (it, rg, l) at byte ((it*4+rg)*64+l)*16.
// Producer of k-pair (j,j+1), batch b writes one dword:
// ---------------------------------------------------------------------------
__device__ __forceinline__ int frag_dw(int b, int j) {
  return (((((j >> 5) * 4 + (b >> 4)) * 4 + ((j >> 3) & 3)) * 16 + (b & 15)) * 4)
         + ((j & 7) >> 1);
}

// W LDS swizzle, full-rank: bits 4-6 from r&7, bits 7-8 from (r>>3)&3.
__device__ __forceinline__ int wswz(int r) {
  return ((r & 7) << 4) | (((r >> 3) & 3) << 7);
}

__device__ __forceinline__ void load_W_lds(unsigned short* Wl,
                                           const __hip_bfloat16* Wg,
                                           int n_base, int K)
{
  int chunksPerRow = (K * 2) / 16;
  int total = 32 * chunksPerRow;
  for (int idx = threadIdx.x; idx < total; idx += 256) {
    int r  = idx / chunksPerRow;
    int cb = (idx % chunksPerRow) * 16;
    bf16x8 v = *(const bf16x8*)((const char*)(Wg + (long)(n_base + r) * K) + cb);
    *(bf16x8*)((char*)Wl + (long)r * (K * 2) + (cb ^ wswz(r))) = v;
  }
}

// ---------------------------------------------------------------------------
// Cached-A MFMA range [kbase, kbase+NIT) (read-only global data)
// ---------------------------------------------------------------------------
__device__ __forceinline__ void mfma_cached(
    const __hip_bfloat16* a0p, int kbase, int NIT,
    const char* w0, const char* w1, int xr0, int xr1, int kk,
    f32x4& acc0, f32x4& acc1)
{
  #pragma unroll 4
  for (int it = kbase; it < kbase + NIT; ++it) {
    bf16x8 av = *(const bf16x8*)(a0p + it * 32 + kk);
    int oo = (it * 32 + kk) * 2;
    bf16x8 bv0 = *(const bf16x8*)(w0 + (oo ^ xr0));
    bf16x8 bv1 = *(const bf16x8*)(w1 + (oo ^ xr1));
    acc0 = __builtin_amdgcn_mfma_f32_16x16x32_bf16(av, bv0, acc0, 0, 0, 0);
    acc1 = __builtin_amdgcn_mfma_f32_16x16x32_bf16(av, bv1, acc1, 0, 0, 0);
  }
}

// Issue 12 coherent 16B frag loads (chunk c0..c0+11) into a register array.
__device__ __forceinline__ void issue12(u32x4* dst, const char* base, int c0) {
  #pragma unroll
  for (int i = 0; i < 12; ++i)
    dst[i] = cload16(base + (size_t)(c0 + i) * 4096);
}

// Compute 12 staged frag iterations (loads already waited).
__device__ __forceinline__ void mfma_st12(
    const u32x4* st, int kbase,
    const char* w0, const char* w1, int xr0, int xr1, int kk,
    f32x4& acc0, f32x4& acc1)
{
  #pragma unroll
  for (int i = 0; i < 12; ++i) {
    int oo = ((kbase + i) * 32 + kk) * 2;
    bf16x8 av = __builtin_bit_cast(bf16x8, st[i]);
    bf16x8 bv0 = *(const bf16x8*)(w0 + (oo ^ xr0));
    bf16x8 bv1 = *(const bf16x8*)(w1 + (oo ^ xr1));
    acc0 = __builtin_amdgcn_mfma_f32_16x16x32_bf16(av, bv0, acc0, 0, 0, 0);
    acc1 = __builtin_amdgcn_mfma_f32_16x16x32_bf16(av, bv1, acc1, 0, 0, 0);
  }
}

// ---------------------------------------------------------------------------
// Fused setup: convert x to bf16 + pack all 4 weight matrices (one launch).
// ---------------------------------------------------------------------------
__device__ __forceinline__ void pack_seg(const float* Wih, const float* Whh,
                                         __hip_bfloat16* dst, int Kih,
                                         long id0, long stride)
{
  int K = Kih + HD;
  long total = (long)NGATE * K;
  for (long idx = id0; idx < total; idx += stride) {
    int np = (int)(idx / K), k = (int)(idx % K);
    int j = np >> 2, g = np & 3;
    int n = g * HD + j;
    float v = (k < Kih) ? Wih[(long)n * Kih + k] : Whh[(long)n * HD + (k - Kih)];
    dst[idx] = __float2bfloat16(v);
  }
}

__global__ void setup_kernel(
    const float* __restrict__ x,
    const float* __restrict__ WihF, const float* __restrict__ WhhF,
    const float* __restrict__ WihB, const float* __restrict__ WhhB,
    const float* __restrict__ WihS, const float* __restrict__ WhhS,
    const float* __restrict__ WihW, const float* __restrict__ WhhW,
    __hip_bfloat16* __restrict__ X16,
    __hip_bfloat16* __restrict__ WF, __hip_bfloat16* __restrict__ WB,
    __hip_bfloat16* __restrict__ WS, __hip_bfloat16* __restrict__ WW)
{
  long id0 = (long)blockIdx.x * blockDim.x + threadIdx.x;
  long stride = (long)gridDim.x * blockDim.x;
  for (long i = id0; i < (long)NB * NT * HD; i += stride)
    X16[i] = __float2bfloat16(x[i]);
  pack_seg(WihF, WhhF, WF, 768, id0, stride);
  pack_seg(WihB, WhhB, WB, 768, id0, stride);
  pack_seg(WihS, WhhS, WS, 1536, id0, stride);
  pack_seg(WihW, WhhW, WW, 1536, id0, stride);
}

__global__ void fill_sentinel(float* out, int n, float v)
{
  int i = blockIdx.x * blockDim.x + threadIdx.x;
  if (i < n) out[i] = v;
}

// ---------------------------------------------------------------------------
// Phase 1 persistent: BiLSTM, 192 blocks (0-95 fwd, 96-191 bwd), 256 steps.
// Per step: cached X16 12 its (covers poll) -> wait -> issue 24 H loads ->
// cached X16 12 its (covers LLC latency) -> vmcnt(0) -> 24 staged its.
// ---------------------------------------------------------------------------
__global__ __launch_bounds__(256, 1) void bilstm_persist(
    const __hip_bfloat16* __restrict__ X16,   // [64][256][768]
    const __hip_bfloat16* __restrict__ WF,
    const __hip_bfloat16* __restrict__ WB,
    const float* __restrict__ bF, const float* __restrict__ bB,
    unsigned* __restrict__ H16u,              // [2 par][2 dir] frag 98304B
    __hip_bfloat16* __restrict__ L16,         // [64][256][1536]
    int* __restrict__ flags)                  // [2 dir][96*FPAD]
{
  __shared__ unsigned short Wl[32 * 1536];    // 96 KiB
  __shared__ float gl[64][33];
  int blk = blockIdx.x, dir = blk / 96, nt = blk % 96;
  load_W_lds(Wl, dir ? WB : WF, nt * 32, 1536);
  const float* bias = dir ? bB : bF;
  int* myflags = flags + dir * 96 * FPAD;
  int tid = threadIdx.x;
  unsigned* L16u = (unsigned*)L16;

  int w = tid >> 6, l = tid & 63, lr = l & 15, lh = l >> 4;
  const char* w0 = (const char*)Wl + lr * 3072;
  const char* w1 = (const char*)Wl + (16 + lr) * 3072;
  int xr0 = wswz(lr), xr1 = wswz(16 + lr);
  int kk = 8 * lh;
  int bA = 16 * w + lr;

  int e0 = tid * 2;
  int b = e0 >> 3, jj = e0 & 7;        // jj even
  int j0 = nt * 8 + jj;
  float bv[2][4];
  #pragma unroll
  for (int u = 0; u < 2; ++u) {
    bv[u][0] = bias[j0 + u];          bv[u][1] = bias[HD + j0 + u];
    bv[u][2] = bias[2 * HD + j0 + u]; bv[u][3] = bias[3 * HD + j0 + u];
  }
  int fdw = frag_dw(b, j0);
  float cst[2] = {0.f, 0.f};
  __syncthreads();

  for (int s = 0; s < NT; ++s) {
    int par = s & 1;
    int t = dir ? (NT - 1 - s) : s;
    const __hip_bfloat16* xb = X16 + (long)t * HD + (long)bA * (NT * HD);
    f32x4 acc0 = {0.f, 0.f, 0.f, 0.f};
    f32x4 acc1 = {0.f, 0.f, 0.f, 0.f};
    mfma_cached(xb, 0, 12, w0, w1, xr0, xr1, kk, acc0, acc1);   // covers poll
    if (s > 0) wait2(myflags, s, nullptr, 0);
    const char* fpH = (const char*)(H16u + (long)(par * 2 + dir) * 24576)
                      + (size_t)(w * 64 + l) * 16;
    u32x4 hA[12], hB[12];
    issue12(hA, fpH, 0);
    issue12(hB, fpH, 12);
    mfma_cached(xb, 12, 12, w0, w1, xr0, xr1, kk, acc0, acc1);  // covers latency
    VMW(0);
    mfma_st12(hA, 24, w0, w1, xr0, xr1, kk, acc0, acc1);
    mfma_st12(hB, 36, w0, w1, xr0, xr1, kk, acc0, acc1);
    #pragma unroll
    for (int r = 0; r < 4; ++r) {
      gl[16 * w + 4 * lh + r][lr]      = acc0[r];
      gl[16 * w + 4 * lh + r][16 + lr] = acc1[r];
    }
    __syncthreads();
    float hv[2];
    #pragma unroll
    for (int u = 0; u < 2; ++u) {
      int col = 4 * (jj + u);
      float vi = gl[b][col + 0] + bv[u][0];
      float vf = gl[b][col + 1] + bv[u][1];
      float vg = gl[b][col + 2] + bv[u][2];
      float vo = gl[b][col + 3] + bv[u][3];
      float si = fast_sig(vi), sf = fast_sig(vf), so = fast_sig(vo);
      float tg = fast_tanh(vg);
      float c = sf * cst[u] + si * tg;
      cst[u] = c;
      hv[u] = so * fast_tanh(c);
    }
    unsigned pk = pack2(hv[0], hv[1]);
    ustore(H16u + (long)((par ^ 1) * 2 + dir) * 24576 + fdw, pk);
    L16u[((long)b * NT + t) * 768 + dir * 384 + (j0 >> 1)] = pk;  // cached (kernel-end flush)
    if (s < NT - 1) arrive_flag(myflags + nt * FPAD);
  }
}

// ---------------------------------------------------------------------------
// cls x-part + pred0; all 256 threads used (k-split halves + shfl reduce)
// ---------------------------------------------------------------------------
__global__ __launch_bounds__(256) void clsx_kernel(
    const __hip_bfloat16* __restrict__ L16,
    const float* __restrict__ clsW, const float* __restrict__ clsb,
    float* __restrict__ out)
{
  int t = blockIdx.x;
  int tid = threadIdx.x;
  int b = tid >> 2, o = (tid >> 1) & 1, hh = tid & 1;
  if (t == 0) {
    if (hh == 0) out[((long)b * NT) * 2 + o] = o ? 1.f : -1.f;
    return;
  }
  const bf16x8* xp = (const bf16x8*)(L16 + ((long)b * NT + t) * 1536 + hh * 768);
  const float* wv = clsW + o * 2304 + HD + hh * 768;
  float s = 0.f;
  for (int k = 0; k < 96; ++k) {
    bf16x8 v = xp[k];
    #pragma unroll
    for (int e = 0; e < 8; ++e)
      s += bf2f((unsigned short)v[e]) * wv[k * 8 + e];
  }
  s += __shfl_down(s, 1);
  if (hh == 0) out[((long)b * NT + t) * 2 + o] = s + clsb[o];
}

// ---------------------------------------------------------------------------
// Phase 2 persistent: 192 blocks (0-95 subword chain, 96-191 word chain),
// producer-consumer via 4-deep SUBW frag ring + flag arrays.
//   subword step s: cached 24 (covers poll); wait flagS>=s & flagW>=s-3;
//                   issue 24 H1 loads; cached 24 (cover); vmcnt(0); staged 24.
//   word    step s: wait flagW>=s; issue 24 H2; wait flagS>=s+1 (loads fly);
//                   3x12 rotating pipeline over 48 SUBW its, counted vmcnt.
// ---------------------------------------------------------------------------
__global__ __launch_bounds__(256, 1) void stack_persist(
    const __hip_bfloat16* __restrict__ L16,
    const __hip_bfloat16* __restrict__ WS,
    const __hip_bfloat16* __restrict__ WW,
    const float* __restrict__ bS, const float* __restrict__ bW,
    const int* __restrict__ golds,
    const float* __restrict__ clsW,
    unsigned* __restrict__ H1Su,   // [2] frag 98304B
    unsigned* __restrict__ H2Su,   // [2] frag 98304B
    unsigned* __restrict__ SUBWu,  // [4] frag 196608B ring (h1 k<768, c1 768..1536)
    float* __restrict__ out,
    int* __restrict__ flags)       // [+2*96*FPAD: S] [+3*96*FPAD: W]
{
  __shared__ unsigned short Wl[32 * 2304];  // 144 KiB
  __shared__ float gl[64][33];
  int blk = blockIdx.x, role = blk / 96, nt = blk % 96;
  int* flagS = flags + 2 * 96 * FPAD;
  int* flagW = flags + 3 * 96 * FPAD;
  const float* bias = role ? bW : bS;
  load_W_lds(Wl, role ? WW : WS, nt * 32, 2304);
  int tid = threadIdx.x;

  int w = tid >> 6, l = tid & 63, lr = l & 15, lh = l >> 4;
  const char* w0 = (const char*)Wl + lr * 4608;
  const char* w1 = (const char*)Wl + (16 + lr) * 4608;
  int xr0 = wswz(lr), xr1 = wswz(16 + lr);
  int kk = 8 * lh;
  int bA = 16 * w + lr;

  int e0 = tid * 2;
  int b = e0 >> 3, jj = e0 & 7;        // jj even
  int j0 = nt * 8 + jj;
  float bv[2][4];
  #pragma unroll
  for (int u = 0; u < 2; ++u) {
    bv[u][0] = bias[j0 + u];          bv[u][1] = bias[HD + j0 + u];
    bv[u][2] = bias[2 * HD + j0 + u]; bv[u][3] = bias[3 * HD + j0 + u];
  }
  const int* gp = golds + b * NT + 1;   // gp[s] = golds[b][s+1]
  int fdw_h = frag_dw(b, j0);
  float cst[2] = {0.f, 0.f};
  float hreg[2] = {0.f, 0.f};
  __syncthreads();

  if (role == 0) {
    // ---- subword chain ----
    int fdw_c = frag_dw(b, 768 + j0);   // c1 at k 768.. in SUBW frag
    for (int s = 0; s < NT - 1; ++s) {
      int g = gp[s];                    // older-than-staging load: safe
      const __hip_bfloat16* lb = L16 + (long)s * 1536 + (long)bA * (NT * 1536);
      f32x4 acc0 = {0.f, 0.f, 0.f, 0.f};
      f32x4 acc1 = {0.f, 0.f, 0.f, 0.f};
      mfma_cached(lb, 0, 24, w0, w1, xr0, xr1, kk, acc0, acc1);   // covers poll
      wait2(flagS, s, flagW, s - 3);
      const char* fpH1 = (const char*)(H1Su + (long)(s & 1) * 24576)
                         + (size_t)(w * 64 + l) * 16;
      u32x4 hA[12], hB[12];
      issue12(hA, fpH1, 0);
      issue12(hB, fpH1, 12);
      mfma_cached(lb, 24, 24, w0, w1, xr0, xr1, kk, acc0, acc1);  // covers latency
      VMW(0);
      mfma_st12(hA, 48, w0, w1, xr0, xr1, kk, acc0, acc1);
      mfma_st12(hB, 60, w0, w1, xr0, xr1, kk, acc0, acc1);
      #pragma unroll
      for (int r = 0; r < 4; ++r) {
        gl[16 * w + 4 * lh + r][lr]      = acc0[r];
        gl[16 * w + 4 * lh + r][16 + lr] = acc1[r];
      }
      __syncthreads();
      float h1v[2], c1v[2];
      #pragma unroll
      for (int u = 0; u < 2; ++u) {
        int col = 4 * (jj + u);
        float vi = gl[b][col + 0] + bv[u][0];
        float vf = gl[b][col + 1] + bv[u][1];
        float vg = gl[b][col + 2] + bv[u][2];
        float vo = gl[b][col + 3] + bv[u][3];
        float si = fast_sig(vi), sf = fast_sig(vf), so = fast_sig(vo);
        float tg = fast_tanh(vg);
        c1v[u] = sf * cst[u] + si * tg;
        h1v[u] = so * fast_tanh(c1v[u]);
      }
      bool push = (g == 0);
      unsigned pkh = pack2(h1v[0], h1v[1]);
      unsigned pkc = pack2(c1v[0], c1v[1]);
      unsigned* sb = SUBWu + (long)(s & 3) * 49152;
      ustore(sb + fdw_h, pkh);
      ustore(sb + fdw_c, pkc);
      ustore(H1Su + (long)((s + 1) & 1) * 24576 + fdw_h, push ? pkh : 0u);
      cst[0] = push ? c1v[0] : 0.f;
      cst[1] = push ? c1v[1] : 0.f;
      arrive_flag(flagS + nt * FPAD);
    }
  } else {
    // ---- word chain: 3x12 rotating deep-prefetch pipeline (36 in flight) ----
    float cw0[2], cw1[2];
    #pragma unroll
    for (int u = 0; u < 2; ++u) { cw0[u] = clsW[j0 + u]; cw1[u] = clsW[2304 + j0 + u]; }
    for (int s = 0; s < NT - 1; ++s) {
      int g = gp[s];                    // older-than-staging load: safe
      wait2(flagW, s, nullptr, 0);      // self-chain: usually already set
      const char* fpH = (const char*)(H2Su + (long)(s & 1) * 24576)
                        + (size_t)(w * 64 + l) * 16;
      const char* fpS = (const char*)(SUBWu + (long)(s & 3) * 49152)
                        + (size_t)(w * 64 + l) * 16;
      u32x4 sA[12], sB[12], sC[12];
      issue12(sA, fpH, 0);              // H2 its 48..59
      issue12(sB, fpH, 12);             // H2 its 60..71
      wait2(flagS, s + 1, nullptr, 0);  // H2 loads drain during poll
      issue12(sC, fpS, 0);              // SUBW its 0..11
      f32x4 acc0 = {0.f, 0.f, 0.f, 0.f};
      f32x4 acc1 = {0.f, 0.f, 0.f, 0.f};
      VMW(24);
      mfma_st12(sA, 48, w0, w1, xr0, xr1, kk, acc0, acc1);
      issue12(sA, fpS, 12);             // SUBW its 12..23
      VMW(24);
      mfma_st12(sB, 60, w0, w1, xr0, xr1, kk, acc0, acc1);
      issue12(sB, fpS, 24);             // SUBW its 24..35
      VMW(24);
      mfma_st12(sC, 0, w0, w1, xr0, xr1, kk, acc0, acc1);
      issue12(sC, fpS, 36);             // SUBW its 36..47
      VMW(24);
      mfma_st12(sA, 12, w0, w1, xr0, xr1, kk, acc0, acc1);
      VMW(12);
      mfma_st12(sB, 24, w0, w1, xr0, xr1, kk, acc0, acc1);
      VMW(0);
      mfma_st12(sC, 36, w0, w1, xr0, xr1, kk, acc0, acc1);
      #pragma unroll
      for (int r = 0; r < 4; ++r) {
        gl[16 * w + 4 * lh + r][lr]      = acc0[r];
        gl[16 * w + 4 * lh + r][16 + lr] = acc1[r];
      }
      __syncthreads();
      float p0 = 0.f, p1 = 0.f;
      float h2v[2], c2v[2];
      #pragma unroll
      for (int u = 0; u < 2; ++u) {
        int col = 4 * (jj + u);
        float vi = gl[b][col + 0] + bv[u][0];
        float vf = gl[b][col + 1] + bv[u][1];
        float vg = gl[b][col + 2] + bv[u][2];
        float vo = gl[b][col + 3] + bv[u][3];
        float si = fast_sig(vi), sf = fast_sig(vf), so = fast_sig(vo);
        float tg = fast_tanh(vg);
        c2v[u] = sf * cst[u] + si * tg;
        h2v[u] = so * fast_tanh(c2v[u]);
        p0 += h2v[u] * cw0[u];
        p1 += h2v[u] * cw1[u];
      }
      bool push = (g >= 1);
      #pragma unroll
      for (int u = 0; u < 2; ++u) {
        cst[u]  = push ? c2v[u] : cst[u];
        hreg[u] = push ? h2v[u] : hreg[u];
      }
      ustore(H2Su + (long)((s + 1) & 1) * 24576 + fdw_h, pack2(hreg[0], hreg[1]));
      p0 += __shfl_down(p0, 1); p1 += __shfl_down(p1, 1);
      p0 += __shfl_down(p0, 2); p1 += __shfl_down(p1, 2);
      if ((tid & 3) == 0) {
        int bb = tid >> 2;
        atomicAdd(&out[((long)bb * NT + s + 1) * 2 + 0], p0);
        atomicAdd(&out[((long)bb * NT + s + 1) * 2 + 1], p1);
      }
      if (s < NT - 2) arrive_flag(flagW + nt * FPAD);
    }
  }
}

// ---------------------------------------------------------------------------
// Host launcher
// ---------------------------------------------------------------------------
extern "C" void kernel_launch(void* const* d_in, const int* in_sizes, int n_in,
                              void* d_out, int out_size, void* d_ws, size_t ws_size,
                              hipStream_t stream)
{
  const float* x     = (const float*)d_in[0];
  const int*   golds = (const int*)d_in[1];
  const float* WihF  = (const float*)d_in[2];
  const float* WhhF  = (const float*)d_in[3];
  const float* bF    = (const float*)d_in[4];
  const float* WihB  = (const float*)d_in[5];
  const float* WhhB  = (const float*)d_in[6];
  const float* bB    = (const float*)d_in[7];
  const float* WihS  = (const float*)d_in[8];
  const float* WhhS  = (const float*)d_in[9];
  const float* bS    = (const float*)d_in[10];
  const float* WihW  = (const float*)d_in[11];
  const float* WhhW  = (const float*)d_in[12];
  const float* bW    = (const float*)d_in[13];
  const float* clsW  = (const float*)d_in[14];
  const float* clsb  = (const float*)d_in[15];
  float* out = (float*)d_out;

  // workspace layout (bytes)
  const size_t OFF_X16  = 0;                   // 25165824
  const size_t OFF_WF   = 25165824;            //  9437184
  const size_t OFF_WB   = 34603008;            //  9437184
  const size_t OFF_WS   = 44040192;            // 14155776
  const size_t OFF_WW   = 58195968;            // 14155776
  const size_t OFF_L16  = 72351744;            // 50331648
  const size_t OFF_H16  = 122683392;           //   393216 (frag [2][2])
  const size_t OFF_H1S  = 123076608;           //   196608 (frag [2])
  const size_t OFF_H2S  = 123273216;           //   196608 (frag [2])
  const size_t OFF_SUBW = 123469824;           //   786432 (frag ring [4])
  const size_t OFF_FLG  = 124256256;           //    49152 (4*96*128B)
  const size_t WS_NEEDED = 124305408;

  if (ws_size < WS_NEEDED) {
    fill_sentinel<<<(out_size + 255) / 256, 256, 0, stream>>>(out, out_size, 12345.f);
    return;
  }

  char* ws = (char*)d_ws;
  __hip_bfloat16* X16  = (__hip_bfloat16*)(ws + OFF_X16);
  __hip_bfloat16* WF   = (__hip_bfloat16*)(ws + OFF_WF);
  __hip_bfloat16* WB   = (__hip_bfloat16*)(ws + OFF_WB);
  __hip_bfloat16* WSp  = (__hip_bfloat16*)(ws + OFF_WS);
  __hip_bfloat16* WWp  = (__hip_bfloat16*)(ws + OFF_WW);
  __hip_bfloat16* L16  = (__hip_bfloat16*)(ws + OFF_L16);
  unsigned*       H16u = (unsigned*)(ws + OFF_H16);
  unsigned*       H1Su = (unsigned*)(ws + OFF_H1S);
  unsigned*       H2Su = (unsigned*)(ws + OFF_H2S);
  unsigned*       SUBWu= (unsigned*)(ws + OFF_SUBW);
  int*            flags= (int*)(ws + OFF_FLG);

  // fused setup: cvt x + pack all 4 weight matrices (one launch)
  setup_kernel<<<4096, 256, 0, stream>>>(x, WihF, WhhF, WihB, WhhB,
                                         WihS, WhhS, WihW, WhhW,
                                         X16, WF, WB, WSp, WWp);
  hipMemsetAsync(ws + OFF_H16, 0, WS_NEEDED - OFF_H16, stream);

  // phase 1: persistent BiLSTM (256 internal flag-sync steps)
  bilstm_persist<<<192, 256, 0, stream>>>(X16, WF, WB, bF, bB, H16u, L16, flags);

  // cls x-part + pred0 (full overwrite of out)
  clsx_kernel<<<NT, 256, 0, stream>>>(L16, clsW, clsb, out);

  // phase 2: persistent stack-LSTM, subword/word chains pipelined
  stack_persist<<<192, 256, 0, stream>>>(L16, WSp, WWp, bS, bW, golds, clsW,
                                         H1Su, H2Su, SUBWu, out, flags);
}

// Round 13
// 4142.035 us; speedup vs baseline: 1.0009x; 1.0005x over previous
//
#include <hip/hip_runtime.h>
#include <hip/hip_bf16.h>

typedef __attribute__((ext_vector_type(8))) short bf16x8;
typedef __attribute__((ext_vector_type(4))) float f32x4;
typedef __attribute__((ext_vector_type(4))) unsigned u32x4;

#define HD   768
#define NB   64
#define NT   256
#define NGATE 3072
#define FPAD 32      // flag padding: 32 ints = 128 B

__device__ __forceinline__ float fast_sig(float x) { return 1.f / (1.f + __expf(-x)); }
__device__ __forceinline__ float fast_tanh(float x) {
  float t = __expf(-2.f * fabsf(x));
  float r = (1.f - t) / (1.f + t);
  return x < 0.f ? -r : r;
}
__device__ __forceinline__ float bf2f(unsigned short u) {
  union { unsigned i; float f; } v; v.i = ((unsigned)u) << 16; return v.f;
}
__device__ __forceinline__ unsigned short f2bfu(float f) {
  union { __hip_bfloat16 b; unsigned short u; } c;
  c.b = __float2bfloat16(f);
  return c.u;
}
__device__ __forceinline__ unsigned pack2(float a, float b) {
  return (unsigned)f2bfu(a) | ((unsigned)f2bfu(b) << 16);
}

#define VMW(N) do { asm volatile("s_waitcnt vmcnt(" #N ")" ::: "memory"); \
                    __builtin_amdgcn_sched_barrier(0); } while (0)

// ---------------------------------------------------------------------------
// Coherent primitives (LLC) + XCD-local (L2) primitives.
// ---------------------------------------------------------------------------
__device__ __forceinline__ int aload(int* p) {
  return __hip_atomic_load(p, __ATOMIC_RELAXED, __HIP_MEMORY_SCOPE_AGENT);
}
__device__ __forceinline__ void ustore(unsigned* p, unsigned v) {
  __hip_atomic_store(p, v, __ATOMIC_RELAXED, __HIP_MEMORY_SCOPE_AGENT);
}
__device__ __forceinline__ int aadd_ret(int* p) {
  return __hip_atomic_fetch_add(p, 1, __ATOMIC_RELAXED, __HIP_MEMORY_SCOPE_AGENT);
}
// 16B load at the coherent point (cross-XCD fresh)
__device__ __forceinline__ u32x4 cload16(const char* p) {
  u32x4 r;
  asm volatile("global_load_dwordx4 %0, %1, off sc0 sc1"
               : "=v"(r) : "v"(p) : "memory");
  return r;
}
// 16B load bypassing L1 only: served by the (shared, XCD-local) L2
__device__ __forceinline__ u32x4 l2load16(const char* p) {
  u32x4 r;
  asm volatile("global_load_dwordx4 %0, %1, off sc0"
               : "=v"(r) : "v"(p) : "memory");
  return r;
}

__device__ __forceinline__ void arrive_flag(int* f) {
  asm volatile("s_waitcnt vmcnt(0)" ::: "memory");
  __syncthreads();
  if (threadIdx.x == 0)
    __hip_atomic_fetch_add(f, 1, __ATOMIC_RELAXED, __HIP_MEMORY_SCOPE_AGENT);
}

__device__ __forceinline__ void wait2(int* fa, int ta, int* fb, int tb) {
  int tid = threadIdx.x;
  int* p = nullptr; int tgt = 0;
  if (tid < 96)                            { p = fa + tid * FPAD;         tgt = ta; }
  else if (fb && tid >= 128 && tid < 224)  { p = fb + (tid - 128) * FPAD; tgt = tb; }
  if (p && tgt > 0) {
    int guard = 0;
    while (aload(p) < tgt) {
      __builtin_amdgcn_s_sleep(1);
      if (++guard > (1 << 17)) break;      // deadlock -> fast wrong answer, not hang
    }
  }
  __syncthreads();
}

// ---------------------------------------------------------------------------
// Frag exchange layout: 16B chunk (it, rg, l) at byte ((it*4+rg)*64+l)*16.
// ---------------------------------------------------------------------------
__device__ __forceinline__ int frag_dw(int b, int j) {
  return (((((j >> 5) * 4 + (b >> 4)) * 4 + ((j >> 3) & 3)) * 16 + (b & 15)) * 4)
         + ((j & 7) >> 1);
}

__device__ __forceinline__ int wswz(int r) {
  return ((r & 7) << 4) | (((r >> 3) & 3) << 7);
}

__device__ __forceinline__ void load_W_lds(unsigned short* Wl,
                                           const __hip_bfloat16* Wg,
                                           int n_base, int K)
{
  int chunksPerRow = (K * 2) / 16;
  int total = 32 * chunksPerRow;
  for (int idx = threadIdx.x; idx < total; idx += 256) {
    int r  = idx / chunksPerRow;
    int cb = (idx % chunksPerRow) * 16;
    bf16x8 v = *(const bf16x8*)((const char*)(Wg + (long)(n_base + r) * K) + cb);
    *(bf16x8*)((char*)Wl + (long)r * (K * 2) + (cb ^ wswz(r))) = v;
  }
}

// Cached-A MFMA range [kbase, kbase+NIT)
__device__ __forceinline__ void mfma_cached(
    const __hip_bfloat16* a0p, int kbase, int NIT,
    const char* w0, const char* w1, int xr0, int xr1, int kk,
    f32x4& acc0, f32x4& acc1)
{
  #pragma unroll 4
  for (int it = kbase; it < kbase + NIT; ++it) {
    bf16x8 av = *(const bf16x8*)(a0p + it * 32 + kk);
    int oo = (it * 32 + kk) * 2;
    bf16x8 bv0 = *(const bf16x8*)(w0 + (oo ^ xr0));
    bf16x8 bv1 = *(const bf16x8*)(w1 + (oo ^ xr1));
    acc0 = __builtin_amdgcn_mfma_f32_16x16x32_bf16(av, bv0, acc0, 0, 0, 0);
    acc1 = __builtin_amdgcn_mfma_f32_16x16x32_bf16(av, bv1, acc1, 0, 0, 0);
  }
}

// Frag-range MFMA from a buffer: CF its, 12-deep dbuf, counted vmcnt.
// L2ONLY=false -> sc0 sc1 (LLC); L2ONLY=true -> sc0 (XCD-local L2 relay).
template<int CF, bool L2ONLY>
__device__ __forceinline__ void mfma_frag(
    const char* Fbase, int l, int w,
    const char* w0, const char* w1, int xr0, int xr1, int kk, int kbase,
    f32x4& acc0, f32x4& acc1)
{
  const char* fp = Fbase + (size_t)(w * 64 + l) * 16;
  u32x4 st[2][12];
  #pragma unroll
  for (int i = 0; i < 12; ++i)
    st[0][i] = L2ONLY ? l2load16(fp + (size_t)i * 4096)
                      : cload16(fp + (size_t)i * 4096);
  #pragma unroll
  for (int c = 0; c < CF / 12; ++c) {
    if (c + 1 < CF / 12) {
      #pragma unroll
      for (int i = 0; i < 12; ++i)
        st[(c + 1) & 1][i] = L2ONLY ? l2load16(fp + (size_t)((c + 1) * 12 + i) * 4096)
                                    : cload16(fp + (size_t)((c + 1) * 12 + i) * 4096);
      asm volatile("s_waitcnt vmcnt(12)" ::: "memory");
    } else {
      asm volatile("s_waitcnt vmcnt(0)" ::: "memory");
    }
    __builtin_amdgcn_sched_barrier(0);
    #pragma unroll
    for (int i = 0; i < 12; ++i) {
      int oo = ((kbase + c * 12 + i) * 32 + kk) * 2;
      bf16x8 av = __builtin_bit_cast(bf16x8, st[c & 1][i]);
      bf16x8 bv0 = *(const bf16x8*)(w0 + (oo ^ xr0));
      bf16x8 bv1 = *(const bf16x8*)(w1 + (oo ^ xr1));
      acc0 = __builtin_amdgcn_mfma_f32_16x16x32_bf16(av, bv0, acc0, 0, 0, 0);
      acc1 = __builtin_amdgcn_mfma_f32_16x16x32_bf16(av, bv1, acc1, 0, 0, 0);
    }
  }
}

// ---------------------------------------------------------------------------
// Fused setup
// ---------------------------------------------------------------------------
__device__ __forceinline__ void pack_seg(const float* Wih, const float* Whh,
                                         __hip_bfloat16* dst, int Kih,
                                         long id0, long stride)
{
  int K = Kih + HD;
  long total = (long)NGATE * K;
  for (long idx = id0; idx < total; idx += stride) {
    int np = (int)(idx / K), k = (int)(idx % K);
    int j = np >> 2, g = np & 3;
    int n = g * HD + j;
    float v = (k < Kih) ? Wih[(long)n * Kih + k] : Whh[(long)n * HD + (k - Kih)];
    dst[idx] = __float2bfloat16(v);
  }
}

__global__ void setup_kernel(
    const float* __restrict__ x,
    const float* __restrict__ WihF, const float* __restrict__ WhhF,
    const float* __restrict__ WihB, const float* __restrict__ WhhB,
    const float* __restrict__ WihS, const float* __restrict__ WhhS,
    const float* __restrict__ WihW, const float* __restrict__ WhhW,
    __hip_bfloat16* __restrict__ X16,
    __hip_bfloat16* __restrict__ WF, __hip_bfloat16* __restrict__ WB,
    __hip_bfloat16* __restrict__ WS, __hip_bfloat16* __restrict__ WW)
{
  long id0 = (long)blockIdx.x * blockDim.x + threadIdx.x;
  long stride = (long)gridDim.x * blockDim.x;
  for (long i = id0; i < (long)NB * NT * HD; i += stride)
    X16[i] = __float2bfloat16(x[i]);
  pack_seg(WihF, WhhF, WF, 768, id0, stride);
  pack_seg(WihB, WhhB, WB, 768, id0, stride);
  pack_seg(WihS, WhhS, WS, 1536, id0, stride);
  pack_seg(WihW, WhhW, WW, 1536, id0, stride);
}

__global__ void fill_sentinel(float* out, int n, float v)
{
  int i = blockIdx.x * blockDim.x + threadIdx.x;
  if (i < n) out[i] = v;
}

// ---------------------------------------------------------------------------
// Phase 1 persistent: BiLSTM (R9 structure — proven fastest).
// ---------------------------------------------------------------------------
__global__ __launch_bounds__(256, 1) void bilstm_persist(
    const __hip_bfloat16* __restrict__ X16,
    const __hip_bfloat16* __restrict__ WF,
    const __hip_bfloat16* __restrict__ WB,
    const float* __restrict__ bF, const float* __restrict__ bB,
    unsigned* __restrict__ H16u,              // [2 par][2 dir] frag 98304B
    __hip_bfloat16* __restrict__ L16,
    int* __restrict__ flags)
{
  __shared__ unsigned short Wl[32 * 1536];
  __shared__ float gl[64][33];
  int blk = blockIdx.x, dir = blk / 96, nt = blk % 96;
  load_W_lds(Wl, dir ? WB : WF, nt * 32, 1536);
  const float* bias = dir ? bB : bF;
  int* myflags = flags + dir * 96 * FPAD;
  int tid = threadIdx.x;
  unsigned* L16u = (unsigned*)L16;

  int w = tid >> 6, l = tid & 63, lr = l & 15, lh = l >> 4;
  const char* w0 = (const char*)Wl + lr * 3072;
  const char* w1 = (const char*)Wl + (16 + lr) * 3072;
  int xr0 = wswz(lr), xr1 = wswz(16 + lr);
  int kk = 8 * lh;
  int bA = 16 * w + lr;

  int e0 = tid * 2;
  int b = e0 >> 3, jj = e0 & 7;
  int j0 = nt * 8 + jj;
  float bv[2][4];
  #pragma unroll
  for (int u = 0; u < 2; ++u) {
    bv[u][0] = bias[j0 + u];          bv[u][1] = bias[HD + j0 + u];
    bv[u][2] = bias[2 * HD + j0 + u]; bv[u][3] = bias[3 * HD + j0 + u];
  }
  int fdw = frag_dw(b, j0);
  float cst[2] = {0.f, 0.f};
  __syncthreads();

  for (int s = 0; s < NT; ++s) {
    int par = s & 1;
    int t = dir ? (NT - 1 - s) : s;
    f32x4 acc0 = {0.f, 0.f, 0.f, 0.f};
    f32x4 acc1 = {0.f, 0.f, 0.f, 0.f};
    mfma_cached(X16 + (long)t * HD + (long)bA * (NT * HD), 0, 24,
                w0, w1, xr0, xr1, kk, acc0, acc1);      // covers poll
    if (s > 0) wait2(myflags, s, nullptr, 0);
    mfma_frag<24, false>((const char*)(H16u + (long)(par * 2 + dir) * 24576),
                         l, w, w0, w1, xr0, xr1, kk, 24, acc0, acc1);
    #pragma unroll
    for (int r = 0; r < 4; ++r) {
      gl[16 * w + 4 * lh + r][lr]      = acc0[r];
      gl[16 * w + 4 * lh + r][16 + lr] = acc1[r];
    }
    __syncthreads();
    float hv[2];
    #pragma unroll
    for (int u = 0; u < 2; ++u) {
      int col = 4 * (jj + u);
      float vi = gl[b][col + 0] + bv[u][0];
      float vf = gl[b][col + 1] + bv[u][1];
      float vg = gl[b][col + 2] + bv[u][2];
      float vo = gl[b][col + 3] + bv[u][3];
      float si = fast_sig(vi), sf = fast_sig(vf), so = fast_sig(vo);
      float tg = fast_tanh(vg);
      float c = sf * cst[u] + si * tg;
      cst[u] = c;
      hv[u] = so * fast_tanh(c);
    }
    unsigned pk = pack2(hv[0], hv[1]);
    ustore(H16u + (long)((par ^ 1) * 2 + dir) * 24576 + fdw, pk);
    L16u[((long)b * NT + t) * 768 + dir * 384 + (j0 >> 1)] = pk;
    if (s < NT - 1) arrive_flag(myflags + nt * FPAD);
  }
}

// ---------------------------------------------------------------------------
// cls x-part + pred0 (all 256 threads)
// ---------------------------------------------------------------------------
__global__ __launch_bounds__(256) void clsx_kernel(
    const __hip_bfloat16* __restrict__ L16,
    const float* __restrict__ clsW, const float* __restrict__ clsb,
    float* __restrict__ out)
{
  int t = blockIdx.x;
  int tid = threadIdx.x;
  int b = tid >> 2, o = (tid >> 1) & 1, hh = tid & 1;
  if (t == 0) {
    if (hh == 0) out[((long)b * NT) * 2 + o] = o ? 1.f : -1.f;
    return;
  }
  const bf16x8* xp = (const bf16x8*)(L16 + ((long)b * NT + t) * 1536 + hh * 768);
  const float* wv = clsW + o * 2304 + HD + hh * 768;
  float s = 0.f;
  for (int k = 0; k < 96; ++k) {
    bf16x8 v = xp[k];
    #pragma unroll
    for (int e = 0; e < 8; ++e)
      s += bf2f((unsigned short)v[e]) * wv[k * 8 + e];
  }
  s += __shfl_down(s, 1);
  if (hh == 0) out[((long)b * NT + t) * 2 + o] = s + clsb[o];
}

// ---------------------------------------------------------------------------
// Phase 2 persistent.
//   subword (blocks 0-95): as R12.
//   word (96-191): per-XCD all-gather relay — co-XCD blocks split the 72-it
//   coherent read, republish into XCD-local L2, then bulk sc0-read from L2.
//   Relay slot s&1; write-safety from flagW>=s; monotonic done-counters.
// ---------------------------------------------------------------------------
__global__ __launch_bounds__(256, 1) void stack_persist(
    const __hip_bfloat16* __restrict__ L16,
    const __hip_bfloat16* __restrict__ WS,
    const __hip_bfloat16* __restrict__ WW,
    const float* __restrict__ bS, const float* __restrict__ bW,
    const int* __restrict__ golds,
    const float* __restrict__ clsW,
    unsigned* __restrict__ H1Su,   // [2] frag 98304B
    unsigned* __restrict__ H2Su,   // [2] frag 98304B
    unsigned* __restrict__ SUBWu,  // [4] frag 196608B ring
    unsigned* __restrict__ relay,  // [16 xcd][2 slot][73728 dw] (aliases X16)
    float* __restrict__ out,
    int* __restrict__ flags)
{
  __shared__ unsigned short Wl[32 * 2304];
  __shared__ float gl[64][33];
  __shared__ int shx[3];
  int blk = blockIdx.x, role = blk / 96, nt = blk % 96;
  int* flagS = flags + 2 * 96 * FPAD;
  int* flagW = flags + 3 * 96 * FPAD;
  int* flagR = flags + 4 * 96 * FPAD;
  int* xreg  = flags + 5 * 96 * FPAD;        // 16 × 32 ints
  int* xdone = xreg + 16 * 32;               // 16 × 32 ints
  const float* bias = role ? bW : bS;
  load_W_lds(Wl, role ? WW : WS, nt * 32, 2304);
  int tid = threadIdx.x;

  int w = tid >> 6, l = tid & 63, lr = l & 15, lh = l >> 4;
  const char* w0 = (const char*)Wl + lr * 4608;
  const char* w1 = (const char*)Wl + (16 + lr) * 4608;
  int xr0 = wswz(lr), xr1 = wswz(16 + lr);
  int kk = 8 * lh;
  int bA = 16 * w + lr;

  int e0 = tid * 2;
  int b = e0 >> 3, jj = e0 & 7;
  int j0 = nt * 8 + jj;
  float bv[2][4];
  #pragma unroll
  for (int u = 0; u < 2; ++u) {
    bv[u][0] = bias[j0 + u];          bv[u][1] = bias[HD + j0 + u];
    bv[u][2] = bias[2 * HD + j0 + u]; bv[u][3] = bias[3 * HD + j0 + u];
  }
  const int* gp = golds + b * NT + 1;
  int fdw_h = frag_dw(b, j0);
  float cst[2] = {0.f, 0.f};
  float hreg[2] = {0.f, 0.f};
  __syncthreads();

  if (role == 0) {
    // ---- subword chain (R12 structure) ----
    int fdw_c = frag_dw(b, 768 + j0);
    for (int s = 0; s < NT - 1; ++s) {
      int g = gp[s];
      const __hip_bfloat16* lb = L16 + (long)s * 1536 + (long)bA * (NT * 1536);
      f32x4 acc0 = {0.f, 0.f, 0.f, 0.f};
      f32x4 acc1 = {0.f, 0.f, 0.f, 0.f};
      mfma_cached(lb, 0, 24, w0, w1, xr0, xr1, kk, acc0, acc1);   // covers poll
      wait2(flagS, s, flagW, s - 3);
      mfma_cached(lb, 24, 24, w0, w1, xr0, xr1, kk, acc0, acc1);
      mfma_frag<24, false>((const char*)(H1Su + (long)(s & 1) * 24576),
                           l, w, w0, w1, xr0, xr1, kk, 48, acc0, acc1);
      #pragma unroll
      for (int r = 0; r < 4; ++r) {
        gl[16 * w + 4 * lh + r][lr]      = acc0[r];
        gl[16 * w + 4 * lh + r][16 + lr] = acc1[r];
      }
      __syncthreads();
      float h1v[2], c1v[2];
      #pragma unroll
      for (int u = 0; u < 2; ++u) {
        int col = 4 * (jj + u);
        float vi = gl[b][col + 0] + bv[u][0];
        float vf = gl[b][col + 1] + bv[u][1];
        float vg = gl[b][col + 2] + bv[u][2];
        float vo = gl[b][col + 3] + bv[u][3];
        float si = fast_sig(vi), sf = fast_sig(vf), so = fast_sig(vo);
        float tg = fast_tanh(vg);
        c1v[u] = sf * cst[u] + si * tg;
        h1v[u] = so * fast_tanh(c1v[u]);
      }
      bool push = (g == 0);
      unsigned pkh = pack2(h1v[0], h1v[1]);
      unsigned pkc = pack2(c1v[0], c1v[1]);
      unsigned* sb = SUBWu + (long)(s & 3) * 49152;
      ustore(sb + fdw_h, pkh);
      ustore(sb + fdw_c, pkc);
      ustore(H1Su + (long)((s + 1) & 1) * 24576 + fdw_h, push ? pkh : 0u);
      cst[0] = push ? c1v[0] : 0.f;
      cst[1] = push ? c1v[1] : 0.f;
      arrive_flag(flagS + nt * FPAD);
    }
  } else {
    // ---- word chain with per-XCD relay ----
    // registration: discover physical XCD, rank within it, member count
    if (tid == 0) {
      unsigned xid;
      asm volatile("s_getreg_b32 %0, hwreg(HW_REG_XCC_ID)" : "=s"(xid));
      xid &= 15;
      shx[0] = (int)xid;
      shx[1] = aadd_ret(xreg + xid * 32);
      __hip_atomic_fetch_add(flagR + nt * FPAD, 1, __ATOMIC_RELAXED,
                             __HIP_MEMORY_SCOPE_AGENT);
    }
    __syncthreads();
    wait2(flagR, 1, nullptr, 0);           // all 96 word blocks registered
    if (tid == 0) shx[2] = aload(xreg + shx[0] * 32);
    __syncthreads();
    int xcd = shx[0], rank = shx[1], cnt = shx[2];
    char* rslot0 = (char*)(relay + (size_t)xcd * 2 * 73728);
    int* mydone = xdone + xcd * 32;
    int off_thr = ((w * 64 + l) * 16);     // thread's 16B offset within a 4KB it

    float cw0[2], cw1[2];
    #pragma unroll
    for (int u = 0; u < 2; ++u) { cw0[u] = clsW[j0 + u]; cw1[u] = clsW[2304 + j0 + u]; }

    for (int s = 0; s < NT - 1; ++s) {
      int g = gp[s];
      wait2(flagW, s, nullptr, 0);         // h2 + relay-slot write safety
      char* rslot = rslot0 + (size_t)(s & 1) * 294912;
      const char* srcH = (const char*)(H2Su + (long)(s & 1) * 24576);
      const char* srcS = (const char*)(SUBWu + (long)(s & 3) * 49152);
      // share read: relay its 48..71 <- H2 (ready now); 0..47 <- SUBW (after flagS)
      u32x4 sv[9]; int itv[9];
      #pragma unroll
      for (int i = 0; i < 9; ++i) {
        int it = rank + i * cnt;
        itv[i] = (it < 72) ? it : 99;
        if (itv[i] >= 48 && itv[i] < 72)
          sv[i] = cload16(srcH + (size_t)(itv[i] - 48) * 4096 + off_thr);
      }
      wait2(flagS, s + 1, nullptr, 0);     // H2 share loads drain during poll
      #pragma unroll
      for (int i = 0; i < 9; ++i)
        if (itv[i] < 48)
          sv[i] = cload16(srcS + (size_t)itv[i] * 4096 + off_thr);
      VMW(0);
      #pragma unroll
      for (int i = 0; i < 9; ++i)
        if (itv[i] < 72)
          *(u32x4*)(rslot + (size_t)itv[i] * 4096 + off_thr) = sv[i];
      // cleanup for unusually small groups (cnt < 8): serial but correct
      for (int it = rank + 9 * cnt; it < 72; it += cnt) {
        u32x4 v = (it >= 48) ? cload16(srcH + (size_t)(it - 48) * 4096 + off_thr)
                             : cload16(srcS + (size_t)it * 4096 + off_thr);
        VMW(0);
        *(u32x4*)(rslot + (size_t)it * 4096 + off_thr) = v;
      }
      asm volatile("s_waitcnt vmcnt(0)" ::: "memory");  // stores in L2
      __syncthreads();
      if (tid == 0) {
        __hip_atomic_fetch_add(mydone, 1, __ATOMIC_RELAXED, __HIP_MEMORY_SCOPE_AGENT);
        int guard = 0, tgtd = cnt * (s + 1);
        while (aload(mydone) < tgtd) {
          __builtin_amdgcn_s_sleep(1);
          if (++guard > (1 << 17)) break;
        }
      }
      __syncthreads();
      // bulk: all 72 its from XCD-local L2 (sc0), pipelined, + MFMA
      f32x4 acc0 = {0.f, 0.f, 0.f, 0.f};
      f32x4 acc1 = {0.f, 0.f, 0.f, 0.f};
      mfma_frag<72, true>(rslot, l, w, w0, w1, xr0, xr1, kk, 0, acc0, acc1);
      #pragma unroll
      for (int r = 0; r < 4; ++r) {
        gl[16 * w + 4 * lh + r][lr]      = acc0[r];
        gl[16 * w + 4 * lh + r][16 + lr] = acc1[r];
      }
      __syncthreads();
      float p0 = 0.f, p1 = 0.f;
      float h2v[2], c2v[2];
      #pragma unroll
      for (int u = 0; u < 2; ++u) {
        int col = 4 * (jj + u);
        float vi = gl[b][col + 0] + bv[u][0];
        float vf = gl[b][col + 1] + bv[u][1];
        float vg = gl[b][col + 2] + bv[u][2];
        float vo = gl[b][col + 3] + bv[u][3];
        float si = fast_sig(vi), sf = fast_sig(vf), so = fast_sig(vo);
        float tg = fast_tanh(vg);
        c2v[u] = sf * cst[u] + si * tg;
        h2v[u] = so * fast_tanh(c2v[u]);
        p0 += h2v[u] * cw0[u];
        p1 += h2v[u] * cw1[u];
      }
      bool push = (g >= 1);
      #pragma unroll
      for (int u = 0; u < 2; ++u) {
        cst[u]  = push ? c2v[u] : cst[u];
        hreg[u] = push ? h2v[u] : hreg[u];
      }
      ustore(H2Su + (long)((s + 1) & 1) * 24576 + fdw_h, pack2(hreg[0], hreg[1]));
      p0 += __shfl_down(p0, 1); p1 += __shfl_down(p1, 1);
      p0 += __shfl_down(p0, 2); p1 += __shfl_down(p1, 2);
      if ((tid & 3) == 0) {
        int bb = tid >> 2;
        atomicAdd(&out[((long)bb * NT + s + 1) * 2 + 0], p0);
        atomicAdd(&out[((long)bb * NT + s + 1) * 2 + 1], p1);
      }
      if (s < NT - 2) arrive_flag(flagW + nt * FPAD);
    }
  }
}

// ---------------------------------------------------------------------------
// Host launcher
// ---------------------------------------------------------------------------
extern "C" void kernel_launch(void* const* d_in, const int* in_sizes, int n_in,
                              void* d_out, int out_size, void* d_ws, size_t ws_size,
                              hipStream_t stream)
{
  const float* x     = (const float*)d_in[0];
  const int*   golds = (const int*)d_in[1];
  const float* WihF  = (const float*)d_in[2];
  const float* WhhF  = (const float*)d_in[3];
  const float* bF    = (const float*)d_in[4];
  const float* WihB  = (const float*)d_in[5];
  const float* WhhB  = (const float*)d_in[6];
  const float* bB    = (const float*)d_in[7];
  const float* WihS  = (const float*)d_in[8];
  const float* WhhS  = (const float*)d_in[9];
  const float* bS    = (const float*)d_in[10];
  const float* WihW  = (const float*)d_in[11];
  const float* WhhW  = (const float*)d_in[12];
  const float* bW    = (const float*)d_in[13];
  const float* clsW  = (const float*)d_in[14];
  const float* clsb  = (const float*)d_in[15];
  float* out = (float*)d_out;

  // workspace layout (bytes)
  const size_t OFF_X16  = 0;                   // 25165824 (relay aliases this in phase 2)
  const size_t OFF_WF   = 25165824;
  const size_t OFF_WB   = 34603008;
  const size_t OFF_WS   = 44040192;
  const size_t OFF_WW   = 58195968;
  const size_t OFF_L16  = 72351744;
  const size_t OFF_H16  = 122683392;           //   393216
  const size_t OFF_H1S  = 123076608;           //   196608
  const size_t OFF_H2S  = 123273216;           //   196608
  const size_t OFF_SUBW = 123469824;           //   786432
  const size_t OFF_FLG  = 124256256;           //   61440 (5 rows) + 4096 counters
  const size_t WS_NEEDED = 124321792;          //   < proven-available 124452864

  if (ws_size < WS_NEEDED) {
    fill_sentinel<<<(out_size + 255) / 256, 256, 0, stream>>>(out, out_size, 12345.f);
    return;
  }

  char* ws = (char*)d_ws;
  __hip_bfloat16* X16  = (__hip_bfloat16*)(ws + OFF_X16);
  __hip_bfloat16* WF   = (__hip_bfloat16*)(ws + OFF_WF);
  __hip_bfloat16* WB   = (__hip_bfloat16*)(ws + OFF_WB);
  __hip_bfloat16* WSp  = (__hip_bfloat16*)(ws + OFF_WS);
  __hip_bfloat16* WWp  = (__hip_bfloat16*)(ws + OFF_WW);
  __hip_bfloat16* L16  = (__hip_bfloat16*)(ws + OFF_L16);
  unsigned*       H16u = (unsigned*)(ws + OFF_H16);
  unsigned*       H1Su = (unsigned*)(ws + OFF_H1S);
  unsigned*       H2Su = (unsigned*)(ws + OFF_H2S);
  unsigned*       SUBWu= (unsigned*)(ws + OFF_SUBW);
  unsigned*       relay= (unsigned*)(ws + OFF_X16);   // phase-2 only
  int*            flags= (int*)(ws + OFF_FLG);

  setup_kernel<<<4096, 256, 0, stream>>>(x, WihF, WhhF, WihB, WhhB,
                                         WihS, WhhS, WihW, WhhW,
                                         X16, WF, WB, WSp, WWp);
  hipMemsetAsync(ws + OFF_H16, 0, WS_NEEDED - OFF_H16, stream);

  bilstm_persist<<<192, 256, 0, stream>>>(X16, WF, WB, bF, bB, H16u, L16, flags);

  clsx_kernel<<<NT, 256, 0, stream>>>(L16, clsW, clsb, out);

  stack_persist<<<192, 256, 0, stream>>>(L16, WSp, WWp, bS, bW, golds, clsW,
                                         H1Su, H2Su, SUBWu, relay, out, flags);
}

// Round 14
// 3884.231 us; speedup vs baseline: 1.0673x; 1.0664x over previous
//
#include <hip/hip_runtime.h>
#include <hip/hip_bf16.h>

typedef __attribute__((ext_vector_type(8))) short bf16x8;
typedef __attribute__((ext_vector_type(4))) float f32x4;
typedef __attribute__((ext_vector_type(4))) unsigned u32x4;

#define HD   768
#define NB   64
#define NT   256
#define NGATE 3072
#define FPAD 32      // flag padding: 32 ints = 128 B

__device__ __forceinline__ float fast_sig(float x) { return 1.f / (1.f + __expf(-x)); }
__device__ __forceinline__ float fast_tanh(float x) {
  float t = __expf(-2.f * fabsf(x));
  float r = (1.f - t) / (1.f + t);
  return x < 0.f ? -r : r;
}
__device__ __forceinline__ float bf2f(unsigned short u) {
  union { unsigned i; float f; } v; v.i = ((unsigned)u) << 16; return v.f;
}
__device__ __forceinline__ unsigned short f2bfu(float f) {
  union { __hip_bfloat16 b; unsigned short u; } c;
  c.b = __float2bfloat16(f);
  return c.u;
}
__device__ __forceinline__ unsigned pack2(float a, float b) {
  return (unsigned)f2bfu(a) | ((unsigned)f2bfu(b) << 16);
}

#define VMW(N) do { asm volatile("s_waitcnt vmcnt(" #N ")" ::: "memory"); \
                    __builtin_amdgcn_sched_barrier(0); } while (0)

// ---------------------------------------------------------------------------
// Coherent-path primitives (LLC, bypass non-cross-coherent per-XCD L2).
// ---------------------------------------------------------------------------
__device__ __forceinline__ int aload(int* p) {
  return __hip_atomic_load(p, __ATOMIC_RELAXED, __HIP_MEMORY_SCOPE_AGENT);
}
__device__ __forceinline__ void ustore(unsigned* p, unsigned v) {
  __hip_atomic_store(p, v, __ATOMIC_RELAXED, __HIP_MEMORY_SCOPE_AGENT);
}
__device__ __forceinline__ void ustore64(unsigned long long* p, unsigned long long v) {
  __hip_atomic_store(p, v, __ATOMIC_RELAXED, __HIP_MEMORY_SCOPE_AGENT);
}
// 16B / 4B coherent loads (cross-XCD fresh)
__device__ __forceinline__ u32x4 cload16(const char* p) {
  u32x4 r;
  asm volatile("global_load_dwordx4 %0, %1, off sc0 sc1"
               : "=v"(r) : "v"(p) : "memory");
  return r;
}
__device__ __forceinline__ unsigned cload4(const char* p) {
  unsigned r;
  asm volatile("global_load_dword %0, %1, off sc0 sc1"
               : "=v"(r) : "v"(p) : "memory");
  return r;
}

__device__ __forceinline__ void arrive_flag(int* f) {
  asm volatile("s_waitcnt vmcnt(0)" ::: "memory");
  __syncthreads();
  if (threadIdx.x == 0)
    __hip_atomic_fetch_add(f, 1, __ATOMIC_RELAXED, __HIP_MEMORY_SCOPE_AGENT);
}

__device__ __forceinline__ void wait2(int* fa, int ta, int* fb, int tb) {
  int tid = threadIdx.x;
  int* p = nullptr; int tgt = 0;
  if (tid < 96)                            { p = fa + tid * FPAD;         tgt = ta; }
  else if (fb && tid >= 128 && tid < 224)  { p = fb + (tid - 128) * FPAD; tgt = tb; }
  if (p && tgt > 0) {
    int guard = 0;
    while (aload(p) < tgt) {
      __builtin_amdgcn_s_sleep(1);
      if (++guard > (1 << 17)) break;      // deadlock -> fast wrong answer, not hang
    }
  }
  __syncthreads();
}

// coarse-grained wait (reducer blocks; long sleep to limit LLC poll traffic)
__device__ __forceinline__ void wait_coarse(int* fa, int t) {
  int tid = threadIdx.x;
  if (tid < 96) {
    int guard = 0;
    while (aload(fa + tid * FPAD) < t) {
      __builtin_amdgcn_s_sleep(127);
      if (++guard > (1 << 15)) break;
    }
  }
  __syncthreads();
}

// ---------------------------------------------------------------------------
// Frag exchange layout: 16B chunk (it, rg, l) at byte ((it*4+rg)*64+l)*16.
// ---------------------------------------------------------------------------
__device__ __forceinline__ int frag_dw(int b, int j) {
  return (((((j >> 5) * 4 + (b >> 4)) * 4 + ((j >> 3) & 3)) * 16 + (b & 15)) * 4)
         + ((j & 7) >> 1);
}

__device__ __forceinline__ int wswz(int r) {
  return ((r & 7) << 4) | (((r >> 3) & 3) << 7);
}

__device__ __forceinline__ void load_W_lds(unsigned short* Wl,
                                           const __hip_bfloat16* Wg,
                                           int n_base, int K)
{
  int chunksPerRow = (K * 2) / 16;
  int total = 32 * chunksPerRow;
  for (int idx = threadIdx.x; idx < total; idx += 256) {
    int r  = idx / chunksPerRow;
    int cb = (idx % chunksPerRow) * 16;
    bf16x8 v = *(const bf16x8*)((const char*)(Wg + (long)(n_base + r) * K) + cb);
    *(bf16x8*)((char*)Wl + (long)r * (K * 2) + (cb ^ wswz(r))) = v;
  }
}

// Cached-A MFMA range [kbase, kbase+NIT)
__device__ __forceinline__ void mfma_cached(
    const __hip_bfloat16* a0p, int kbase, int NIT,
    const char* w0, const char* w1, int xr0, int xr1, int kk,
    f32x4& acc0, f32x4& acc1)
{
  #pragma unroll 4
  for (int it = kbase; it < kbase + NIT; ++it) {
    bf16x8 av = *(const bf16x8*)(a0p + it * 32 + kk);
    int oo = (it * 32 + kk) * 2;
    bf16x8 bv0 = *(const bf16x8*)(w0 + (oo ^ xr0));
    bf16x8 bv1 = *(const bf16x8*)(w1 + (oo ^ xr1));
    acc0 = __builtin_amdgcn_mfma_f32_16x16x32_bf16(av, bv0, acc0, 0, 0, 0);
    acc1 = __builtin_amdgcn_mfma_f32_16x16x32_bf16(av, bv1, acc1, 0, 0, 0);
  }
}

// Frag-range MFMA: CF its (multiple of 12), 12-deep dbuf, counted vmcnt.
template<int CF>
__device__ __forceinline__ void mfma_frag(
    const char* Fbase, int l, int w,
    const char* w0, const char* w1, int xr0, int xr1, int kk, int kbase,
    f32x4& acc0, f32x4& acc1)
{
  const char* fp = Fbase + (size_t)(w * 64 + l) * 16;
  u32x4 st[2][12];
  #pragma unroll
  for (int i = 0; i < 12; ++i)
    st[0][i] = cload16(fp + (size_t)i * 4096);
  #pragma unroll
  for (int c = 0; c < CF / 12; ++c) {
    if (c + 1 < CF / 12) {
      #pragma unroll
      for (int i = 0; i < 12; ++i)
        st[(c + 1) & 1][i] = cload16(fp + (size_t)((c + 1) * 12 + i) * 4096);
      asm volatile("s_waitcnt vmcnt(12)" ::: "memory");
    } else {
      asm volatile("s_waitcnt vmcnt(0)" ::: "memory");
    }
    __builtin_amdgcn_sched_barrier(0);
    #pragma unroll
    for (int i = 0; i < 12; ++i) {
      int oo = ((kbase + c * 12 + i) * 32 + kk) * 2;
      bf16x8 av = __builtin_bit_cast(bf16x8, st[c & 1][i]);
      bf16x8 bv0 = *(const bf16x8*)(w0 + (oo ^ xr0));
      bf16x8 bv1 = *(const bf16x8*)(w1 + (oo ^ xr1));
      acc0 = __builtin_amdgcn_mfma_f32_16x16x32_bf16(av, bv0, acc0, 0, 0, 0);
      acc1 = __builtin_amdgcn_mfma_f32_16x16x32_bf16(av, bv1, acc1, 0, 0, 0);
    }
  }
}

// Issue 12 coherent 16B frag loads into a register array.
__device__ __forceinline__ void issue12(u32x4* dst, const char* base, int c0) {
  #pragma unroll
  for (int i = 0; i < 12; ++i)
    dst[i] = cload16(base + (size_t)(c0 + i) * 4096);
}

// Compute 12 staged frag iterations (loads already waited).
__device__ __forceinline__ void mfma_st12(
    const u32x4* st, int kbase,
    const char* w0, const char* w1, int xr0, int xr1, int kk,
    f32x4& acc0, f32x4& acc1)
{
  #pragma unroll
  for (int i = 0; i < 12; ++i) {
    int oo = ((kbase + i) * 32 + kk) * 2;
    bf16x8 av = __builtin_bit_cast(bf16x8, st[i]);
    bf16x8 bv0 = *(const bf16x8*)(w0 + (oo ^ xr0));
    bf16x8 bv1 = *(const bf16x8*)(w1 + (oo ^ xr1));
    acc0 = __builtin_amdgcn_mfma_f32_16x16x32_bf16(av, bv0, acc0, 0, 0, 0);
    acc1 = __builtin_amdgcn_mfma_f32_16x16x32_bf16(av, bv1, acc1, 0, 0, 0);
  }
}

// ---------------------------------------------------------------------------
// Fused setup
// ---------------------------------------------------------------------------
__device__ __forceinline__ void pack_seg(const float* Wih, const float* Whh,
                                         __hip_bfloat16* dst, int Kih,
                                         long id0, long stride)
{
  int K = Kih + HD;
  long total = (long)NGATE * K;
  for (long idx = id0; idx < total; idx += stride) {
    int np = (int)(idx / K), k = (int)(idx % K);
    int j = np >> 2, g = np & 3;
    int n = g * HD + j;
    float v = (k < Kih) ? Wih[(long)n * Kih + k] : Whh[(long)n * HD + (k - Kih)];
    dst[idx] = __float2bfloat16(v);
  }
}

__global__ void setup_kernel(
    const float* __restrict__ x,
    const float* __restrict__ WihF, const float* __restrict__ WhhF,
    const float* __restrict__ WihB, const float* __restrict__ WhhB,
    const float* __restrict__ WihS, const float* __restrict__ WhhS,
    const float* __restrict__ WihW, const float* __restrict__ WhhW,
    __hip_bfloat16* __restrict__ X16,
    __hip_bfloat16* __restrict__ WF, __hip_bfloat16* __restrict__ WB,
    __hip_bfloat16* __restrict__ WS, __hip_bfloat16* __restrict__ WW)
{
  long id0 = (long)blockIdx.x * blockDim.x + threadIdx.x;
  long stride = (long)gridDim.x * blockDim.x;
  for (long i = id0; i < (long)NB * NT * HD; i += stride)
    X16[i] = __float2bfloat16(x[i]);
  pack_seg(WihF, WhhF, WF, 768, id0, stride);
  pack_seg(WihB, WhhB, WB, 768, id0, stride);
  pack_seg(WihS, WhhS, WS, 1536, id0, stride);
  pack_seg(WihW, WhhW, WW, 1536, id0, stride);
}

__global__ void fill_sentinel(float* out, int n, float v)
{
  int i = blockIdx.x * blockDim.x + threadIdx.x;
  if (i < n) out[i] = v;
}

// ---------------------------------------------------------------------------
// Phase 1 persistent: BiLSTM (R9 structure — proven fastest).
// ---------------------------------------------------------------------------
__global__ __launch_bounds__(256, 1) void bilstm_persist(
    const __hip_bfloat16* __restrict__ X16,
    const __hip_bfloat16* __restrict__ WF,
    const __hip_bfloat16* __restrict__ WB,
    const float* __restrict__ bF, const float* __restrict__ bB,
    unsigned* __restrict__ H16u,              // [2 par][2 dir] frag 98304B
    __hip_bfloat16* __restrict__ L16,
    int* __restrict__ flags)
{
  __shared__ unsigned short Wl[32 * 1536];
  __shared__ float gl[64][33];
  int blk = blockIdx.x, dir = blk / 96, nt = blk % 96;
  load_W_lds(Wl, dir ? WB : WF, nt * 32, 1536);
  const float* bias = dir ? bB : bF;
  int* myflags = flags + dir * 96 * FPAD;
  int tid = threadIdx.x;
  unsigned* L16u = (unsigned*)L16;

  int w = tid >> 6, l = tid & 63, lr = l & 15, lh = l >> 4;
  const char* w0 = (const char*)Wl + lr * 3072;
  const char* w1 = (const char*)Wl + (16 + lr) * 3072;
  int xr0 = wswz(lr), xr1 = wswz(16 + lr);
  int kk = 8 * lh;
  int bA = 16 * w + lr;

  int e0 = tid * 2;
  int b = e0 >> 3, jj = e0 & 7;
  int j0 = nt * 8 + jj;
  float bv[2][4];
  #pragma unroll
  for (int u = 0; u < 2; ++u) {
    bv[u][0] = bias[j0 + u];          bv[u][1] = bias[HD + j0 + u];
    bv[u][2] = bias[2 * HD + j0 + u]; bv[u][3] = bias[3 * HD + j0 + u];
  }
  int fdw = frag_dw(b, j0);
  float cst[2] = {0.f, 0.f};
  __syncthreads();

  for (int s = 0; s < NT; ++s) {
    int par = s & 1;
    int t = dir ? (NT - 1 - s) : s;
    f32x4 acc0 = {0.f, 0.f, 0.f, 0.f};
    f32x4 acc1 = {0.f, 0.f, 0.f, 0.f};
    mfma_cached(X16 + (long)t * HD + (long)bA * (NT * HD), 0, 24,
                w0, w1, xr0, xr1, kk, acc0, acc1);      // covers poll
    if (s > 0) wait2(myflags, s, nullptr, 0);
    mfma_frag<24>((const char*)(H16u + (long)(par * 2 + dir) * 24576),
                  l, w, w0, w1, xr0, xr1, kk, 24, acc0, acc1);
    #pragma unroll
    for (int r = 0; r < 4; ++r) {
      gl[16 * w + 4 * lh + r][lr]      = acc0[r];
      gl[16 * w + 4 * lh + r][16 + lr] = acc1[r];
    }
    __syncthreads();
    float hv[2];
    #pragma unroll
    for (int u = 0; u < 2; ++u) {
      int col = 4 * (jj + u);
      float vi = gl[b][col + 0] + bv[u][0];
      float vf = gl[b][col + 1] + bv[u][1];
      float vg = gl[b][col + 2] + bv[u][2];
      float vo = gl[b][col + 3] + bv[u][3];
      float si = fast_sig(vi), sf = fast_sig(vf), so = fast_sig(vo);
      float tg = fast_tanh(vg);
      float c = sf * cst[u] + si * tg;
      cst[u] = c;
      hv[u] = so * fast_tanh(c);
    }
    unsigned pk = pack2(hv[0], hv[1]);
    ustore(H16u + (long)((par ^ 1) * 2 + dir) * 24576 + fdw, pk);
    L16u[((long)b * NT + t) * 768 + dir * 384 + (j0 >> 1)] = pk;
    if (s < NT - 1) arrive_flag(myflags + nt * FPAD);
  }
}

// ---------------------------------------------------------------------------
// Phase 2 persistent, grid 256:
//   blocks 0-95   subword chain (R12 structure)
//   blocks 96-191 word chain (R12 3x12 rotation), cls partials -> OUTC scratch
//                 (contention-free 8B stores; NO atomics), arrives every step
//   blocks 192-255 clsx for 4 t-values each, then reduce OUTC into out as
//                 word steps complete (coarse flagW poll; off critical path)
// ---------------------------------------------------------------------------
__global__ __launch_bounds__(256, 1) void stack_persist(
    const __hip_bfloat16* __restrict__ L16,
    const __hip_bfloat16* __restrict__ WS,
    const __hip_bfloat16* __restrict__ WW,
    const float* __restrict__ bS, const float* __restrict__ bW,
    const int* __restrict__ golds,
    const float* __restrict__ clsW, const float* __restrict__ clsb,
    unsigned* __restrict__ H1Su,   // [2] frag 98304B
    unsigned* __restrict__ H2Su,   // [2] frag 98304B
    unsigned* __restrict__ SUBWu,  // [4] frag 196608B ring
    float* __restrict__ OUTC,      // [255][96][128] f32 scratch (aliases X16)
    float* __restrict__ out,
    int* __restrict__ flags)
{
  __shared__ unsigned short Wl[32 * 2304];
  __shared__ float gl[64][33];
  int blk = blockIdx.x, role = blk / 96, nt = blk % 96;
  int* flagS = flags + 2 * 96 * FPAD;
  int* flagW = flags + 3 * 96 * FPAD;
  int tid = threadIdx.x;

  if (role == 2) {
    // ---- clsx + OUTC reducer ----
    int q = blk - 192;
    int b = tid >> 2, o = (tid >> 1) & 1, hh = tid & 1;
    #pragma unroll
    for (int i = 0; i < 4; ++i) {
      int t = q * 4 + i;
      if (t == 0) {
        if (hh == 0) out[((long)b * NT) * 2 + o] = o ? 1.f : -1.f;
      } else {
        const bf16x8* xp = (const bf16x8*)(L16 + ((long)b * NT + t) * 1536 + hh * 768);
        const float* wv = clsW + o * 2304 + HD + hh * 768;
        float s = 0.f;
        for (int k = 0; k < 96; ++k) {
          bf16x8 v = xp[k];
          #pragma unroll
          for (int e = 0; e < 8; ++e)
            s += bf2f((unsigned short)v[e]) * wv[k * 8 + e];
        }
        s += __shfl_down(s, 1);
        if (hh == 0) out[((long)b * NT + t) * 2 + o] = s + clsb[o];
      }
    }
    // reduce owned positions in ascending t
    for (int i = 0; i < 4; ++i) {
      int t = q * 4 + i;
      if (t < 1) continue;
      int sstep = t - 1;
      wait_coarse(flagW, t);             // word step t-1 complete on all blocks
      if (tid < 128) {
        const char* bp = (const char*)OUTC + (((size_t)sstep * 96) * 128 + tid) * 4;
        float acc = 0.f;
        unsigned bufA[12], bufB[12];
        #pragma unroll
        for (int k = 0; k < 12; ++k) bufA[k] = cload4(bp + (size_t)k * 512);
        #pragma unroll
        for (int c = 0; c < 8; ++c) {
          if (c + 1 < 8) {
            if ((c & 1) == 0) {
              #pragma unroll
              for (int k = 0; k < 12; ++k)
                bufB[k] = cload4(bp + (size_t)((c + 1) * 12 + k) * 512);
            } else {
              #pragma unroll
              for (int k = 0; k < 12; ++k)
                bufA[k] = cload4(bp + (size_t)((c + 1) * 12 + k) * 512);
            }
            VMW(12);
          } else {
            VMW(0);
          }
          if ((c & 1) == 0) {
            #pragma unroll
            for (int k = 0; k < 12; ++k) acc += __builtin_bit_cast(float, bufA[k]);
          } else {
            #pragma unroll
            for (int k = 0; k < 12; ++k) acc += __builtin_bit_cast(float, bufB[k]);
          }
        }
        out[((long)(tid >> 1) * NT + t) * 2 + (tid & 1)] += acc;
      }
    }
    return;
  }

  const float* bias = role ? bW : bS;
  load_W_lds(Wl, role ? WW : WS, nt * 32, 2304);

  int w = tid >> 6, l = tid & 63, lr = l & 15, lh = l >> 4;
  const char* w0 = (const char*)Wl + lr * 4608;
  const char* w1 = (const char*)Wl + (16 + lr) * 4608;
  int xr0 = wswz(lr), xr1 = wswz(16 + lr);
  int kk = 8 * lh;
  int bA = 16 * w + lr;

  int e0 = tid * 2;
  int b = e0 >> 3, jj = e0 & 7;
  int j0 = nt * 8 + jj;
  float bv[2][4];
  #pragma unroll
  for (int u = 0; u < 2; ++u) {
    bv[u][0] = bias[j0 + u];          bv[u][1] = bias[HD + j0 + u];
    bv[u][2] = bias[2 * HD + j0 + u]; bv[u][3] = bias[3 * HD + j0 + u];
  }
  const int* gp = golds + b * NT + 1;
  int fdw_h = frag_dw(b, j0);
  float cst[2] = {0.f, 0.f};
  float hreg[2] = {0.f, 0.f};
  __syncthreads();

  if (role == 0) {
    // ---- subword chain ----
    int fdw_c = frag_dw(b, 768 + j0);
    for (int s = 0; s < NT - 1; ++s) {
      int g = gp[s];
      const __hip_bfloat16* lb = L16 + (long)s * 1536 + (long)bA * (NT * 1536);
      f32x4 acc0 = {0.f, 0.f, 0.f, 0.f};
      f32x4 acc1 = {0.f, 0.f, 0.f, 0.f};
      mfma_cached(lb, 0, 24, w0, w1, xr0, xr1, kk, acc0, acc1);   // covers poll
      wait2(flagS, s, flagW, s - 3);
      mfma_cached(lb, 24, 24, w0, w1, xr0, xr1, kk, acc0, acc1);
      mfma_frag<24>((const char*)(H1Su + (long)(s & 1) * 24576),
                    l, w, w0, w1, xr0, xr1, kk, 48, acc0, acc1);
      #pragma unroll
      for (int r = 0; r < 4; ++r) {
        gl[16 * w + 4 * lh + r][lr]      = acc0[r];
        gl[16 * w + 4 * lh + r][16 + lr] = acc1[r];
      }
      __syncthreads();
      float h1v[2], c1v[2];
      #pragma unroll
      for (int u = 0; u < 2; ++u) {
        int col = 4 * (jj + u);
        float vi = gl[b][col + 0] + bv[u][0];
        float vf = gl[b][col + 1] + bv[u][1];
        float vg = gl[b][col + 2] + bv[u][2];
        float vo = gl[b][col + 3] + bv[u][3];
        float si = fast_sig(vi), sf = fast_sig(vf), so = fast_sig(vo);
        float tg = fast_tanh(vg);
        c1v[u] = sf * cst[u] + si * tg;
        h1v[u] = so * fast_tanh(c1v[u]);
      }
      bool push = (g == 0);
      unsigned pkh = pack2(h1v[0], h1v[1]);
      unsigned pkc = pack2(c1v[0], c1v[1]);
      unsigned* sb = SUBWu + (long)(s & 3) * 49152;
      ustore(sb + fdw_h, pkh);
      ustore(sb + fdw_c, pkc);
      ustore(H1Su + (long)((s + 1) & 1) * 24576 + fdw_h, push ? pkh : 0u);
      cst[0] = push ? c1v[0] : 0.f;
      cst[1] = push ? c1v[1] : 0.f;
      arrive_flag(flagS + nt * FPAD);
    }
  } else {
    // ---- word chain: 3x12 rotating deep-prefetch, OUTC scratch (no atomics) ----
    float cw0[2], cw1[2];
    #pragma unroll
    for (int u = 0; u < 2; ++u) { cw0[u] = clsW[j0 + u]; cw1[u] = clsW[2304 + j0 + u]; }
    for (int s = 0; s < NT - 1; ++s) {
      int g = gp[s];
      wait2(flagW, s, nullptr, 0);      // self-chain: usually already set
      const char* fpH = (const char*)(H2Su + (long)(s & 1) * 24576)
                        + (size_t)(w * 64 + l) * 16;
      const char* fpS = (const char*)(SUBWu + (long)(s & 3) * 49152)
                        + (size_t)(w * 64 + l) * 16;
      u32x4 sA[12], sB[12], sC[12];
      issue12(sA, fpH, 0);              // H2 its 48..59
      issue12(sB, fpH, 12);             // H2 its 60..71
      wait2(flagS, s + 1, nullptr, 0);  // H2 loads drain during poll
      issue12(sC, fpS, 0);              // SUBW its 0..11
      f32x4 acc0 = {0.f, 0.f, 0.f, 0.f};
      f32x4 acc1 = {0.f, 0.f, 0.f, 0.f};
      VMW(24);
      mfma_st12(sA, 48, w0, w1, xr0, xr1, kk, acc0, acc1);
      issue12(sA, fpS, 12);             // SUBW its 12..23
      VMW(24);
      mfma_st12(sB, 60, w0, w1, xr0, xr1, kk, acc0, acc1);
      issue12(sB, fpS, 24);             // SUBW its 24..35
      VMW(24);
      mfma_st12(sC, 0, w0, w1, xr0, xr1, kk, acc0, acc1);
      issue12(sC, fpS, 36);             // SUBW its 36..47
      VMW(24);
      mfma_st12(sA, 12, w0, w1, xr0, xr1, kk, acc0, acc1);
      VMW(12);
      mfma_st12(sB, 24, w0, w1, xr0, xr1, kk, acc0, acc1);
      VMW(0);
      mfma_st12(sC, 36, w0, w1, xr0, xr1, kk, acc0, acc1);
      #pragma unroll
      for (int r = 0; r < 4; ++r) {
        gl[16 * w + 4 * lh + r][lr]      = acc0[r];
        gl[16 * w + 4 * lh + r][16 + lr] = acc1[r];
      }
      __syncthreads();
      float p0 = 0.f, p1 = 0.f;
      float h2v[2], c2v[2];
      #pragma unroll
      for (int u = 0; u < 2; ++u) {
        int col = 4 * (jj + u);
        float vi = gl[b][col + 0] + bv[u][0];
        float vf = gl[b][col + 1] + bv[u][1];
        float vg = gl[b][col + 2] + bv[u][2];
        float vo = gl[b][col + 3] + bv[u][3];
        float si = fast_sig(vi), sf = fast_sig(vf), so = fast_sig(vo);
        float tg = fast_tanh(vg);
        c2v[u] = sf * cst[u] + si * tg;
        h2v[u] = so * fast_tanh(c2v[u]);
        p0 += h2v[u] * cw0[u];
        p1 += h2v[u] * cw1[u];
      }
      bool push = (g >= 1);
      #pragma unroll
      for (int u = 0; u < 2; ++u) {
        cst[u]  = push ? c2v[u] : cst[u];
        hreg[u] = push ? h2v[u] : hreg[u];
      }
      ustore(H2Su + (long)((s + 1) & 1) * 24576 + fdw_h, pack2(hreg[0], hreg[1]));
      p0 += __shfl_down(p0, 1); p1 += __shfl_down(p1, 1);
      p0 += __shfl_down(p0, 2); p1 += __shfl_down(p1, 2);
      if ((tid & 3) == 0) {
        int bb = tid >> 2;
        union { float f[2]; unsigned long long u; } pkc;
        pkc.f[0] = p0; pkc.f[1] = p1;
        ustore64((unsigned long long*)&OUTC[(((size_t)s * 96) + nt) * 128 + bb * 2],
                 pkc.u);
      }
      arrive_flag(flagW + nt * FPAD);   // every step (reducers need final count)
    }
  }
}

// ---------------------------------------------------------------------------
// Host launcher
// ---------------------------------------------------------------------------
extern "C" void kernel_launch(void* const* d_in, const int* in_sizes, int n_in,
                              void* d_out, int out_size, void* d_ws, size_t ws_size,
                              hipStream_t stream)
{
  const float* x     = (const float*)d_in[0];
  const int*   golds = (const int*)d_in[1];
  const float* WihF  = (const float*)d_in[2];
  const float* WhhF  = (const float*)d_in[3];
  const float* bF    = (const float*)d_in[4];
  const float* WihB  = (const float*)d_in[5];
  const float* WhhB  = (const float*)d_in[6];
  const float* bB    = (const float*)d_in[7];
  const float* WihS  = (const float*)d_in[8];
  const float* WhhS  = (const float*)d_in[9];
  const float* bS    = (const float*)d_in[10];
  const float* WihW  = (const float*)d_in[11];
  const float* WhhW  = (const float*)d_in[12];
  const float* bW    = (const float*)d_in[13];
  const float* clsW  = (const float*)d_in[14];
  const float* clsb  = (const float*)d_in[15];
  float* out = (float*)d_out;

  // workspace layout (bytes)
  const size_t OFF_X16  = 0;                   // 25165824 (OUTC aliases in phase 2)
  const size_t OFF_WF   = 25165824;
  const size_t OFF_WB   = 34603008;
  const size_t OFF_WS   = 44040192;
  const size_t OFF_WW   = 58195968;
  const size_t OFF_L16  = 72351744;
  const size_t OFF_H16  = 122683392;           //   393216
  const size_t OFF_H1S  = 123076608;           //   196608
  const size_t OFF_H2S  = 123273216;           //   196608
  const size_t OFF_SUBW = 123469824;           //   786432
  const size_t OFF_FLG  = 124256256;           //    49152 (4*96*128B)
  const size_t WS_NEEDED = 124305408;

  if (ws_size < WS_NEEDED) {
    fill_sentinel<<<(out_size + 255) / 256, 256, 0, stream>>>(out, out_size, 12345.f);
    return;
  }

  char* ws = (char*)d_ws;
  __hip_bfloat16* X16  = (__hip_bfloat16*)(ws + OFF_X16);
  __hip_bfloat16* WF   = (__hip_bfloat16*)(ws + OFF_WF);
  __hip_bfloat16* WB   = (__hip_bfloat16*)(ws + OFF_WB);
  __hip_bfloat16* WSp  = (__hip_bfloat16*)(ws + OFF_WS);
  __hip_bfloat16* WWp  = (__hip_bfloat16*)(ws + OFF_WW);
  __hip_bfloat16* L16  = (__hip_bfloat16*)(ws + OFF_L16);
  unsigned*       H16u = (unsigned*)(ws + OFF_H16);
  unsigned*       H1Su = (unsigned*)(ws + OFF_H1S);
  unsigned*       H2Su = (unsigned*)(ws + OFF_H2S);
  unsigned*       SUBWu= (unsigned*)(ws + OFF_SUBW);
  float*          OUTC = (float*)(ws + OFF_X16);   // phase-2 only (12.5 MB < 25 MB)
  int*            flags= (int*)(ws + OFF_FLG);

  setup_kernel<<<4096, 256, 0, stream>>>(x, WihF, WhhF, WihB, WhhB,
                                         WihS, WhhS, WihW, WhhW,
                                         X16, WF, WB, WSp, WWp);
  hipMemsetAsync(ws + OFF_H16, 0, WS_NEEDED - OFF_H16, stream);

  bilstm_persist<<<192, 256, 0, stream>>>(X16, WF, WB, bF, bB, H16u, L16, flags);

  stack_persist<<<256, 256, 0, stream>>>(L16, WSp, WWp, bS, bW, golds,
                                         clsW, clsb, H1Su, H2Su, SUBWu,
                                         OUTC, out, flags);
}